// Round 5
// baseline (419.883 us; speedup 1.0000x reference)
//
#include <hip/hip_runtime.h>
#include <math.h>

// Problem constants
#define BB 2
#define SS 2048
#define EE 2048
#define HH 16
#define DD 128
#define FF 6144   // 3*E

typedef __attribute__((ext_vector_type(8))) short short8;
typedef __attribute__((ext_vector_type(4))) float floatx4;

static __device__ __forceinline__ unsigned short f2bf(float x) {
  unsigned u = __float_as_uint(x);
  u += 0x7fffu + ((u >> 16) & 1u);
  return (unsigned short)(u >> 16);
}
static __device__ __forceinline__ float bf2f(unsigned short h) {
  return __uint_as_float((unsigned)h << 16);
}

#define GLOAD_LDS16(gp, lp)                                       \
  __builtin_amdgcn_global_load_lds(                               \
      (const __attribute__((address_space(1))) void*)(gp),        \
      (__attribute__((address_space(3))) void*)(lp), 16, 0, 0)

// ---------------------------------------------------------------------------
// fp32 -> bf16 cast (float4 in, ushort4 out)
// ---------------------------------------------------------------------------
__global__ __launch_bounds__(256) void cast_f32_bf16(
    const float* __restrict__ in, unsigned short* __restrict__ out, int n4) {
  const int i = blockIdx.x * 256 + threadIdx.x;
  if (i >= n4) return;
  const float4 v = ((const float4*)in)[i];
  ushort4 o;
  o.x = f2bf(v.x); o.y = f2bf(v.y); o.z = f2bf(v.z); o.w = f2bf(v.w);
  ((ushort4*)out)[i] = o;
}

static __device__ __forceinline__ void store_out(float* p, float v) { *p = v; }
static __device__ __forceinline__ void store_out(unsigned short* p, float v) {
  *p = f2bf(v);
}

// ---------------------------------------------------------------------------
// bf16 MFMA GEMM, double-buffered 128^2 (kept for the out-projection).
// ---------------------------------------------------------------------------
template <typename OutT>
__global__ __launch_bounds__(256) void gemm_bf16_mfma(
    const unsigned short* __restrict__ A, const unsigned short* __restrict__ Bt,
    const float* __restrict__ bias, OutT* __restrict__ C,
    int M, int N, int K) {
  __shared__ unsigned short As[2][128][32];
  __shared__ unsigned short Bs[2][128][32];
  const int tid = threadIdx.x;
  const int L = tid & 63;
  const int w = tid >> 6;
  const int m0 = blockIdx.y * 128;
  const int n0 = blockIdx.x * 128;

  const int i0 = w * 2;
  const int lrow = L >> 2;
  const int lcol = (L & 3) * 8;
  const size_t a_off0 = (size_t)(m0 + (i0 + 0) * 16 + lrow) * K + lcol;
  const size_t a_off1 = (size_t)(m0 + (i0 + 1) * 16 + lrow) * K + lcol;
  const size_t b_off0 = (size_t)(n0 + (i0 + 0) * 16 + lrow) * K + lcol;
  const size_t b_off1 = (size_t)(n0 + (i0 + 1) * 16 + lrow) * K + lcol;

  const int wr = (w >> 1) * 64;
  const int wc = (w & 1) * 64;
  const int lane16 = L & 15;
  const int quad = L >> 4;

  floatx4 acc[4][4] = {};

  GLOAD_LDS16(A + a_off0, &As[0][(i0 + 0) * 16][0]);
  GLOAD_LDS16(A + a_off1, &As[0][(i0 + 1) * 16][0]);
  GLOAD_LDS16(Bt + b_off0, &Bs[0][(i0 + 0) * 16][0]);
  GLOAD_LDS16(Bt + b_off1, &Bs[0][(i0 + 1) * 16][0]);

  for (int k0 = 0; k0 < K; k0 += 32) {
    const int cur = (k0 >> 5) & 1;
    __syncthreads();
    if (k0 + 32 < K) {
      const int nxt = cur ^ 1;
      GLOAD_LDS16(A + a_off0 + k0 + 32, &As[nxt][(i0 + 0) * 16][0]);
      GLOAD_LDS16(A + a_off1 + k0 + 32, &As[nxt][(i0 + 1) * 16][0]);
      GLOAD_LDS16(Bt + b_off0 + k0 + 32, &Bs[nxt][(i0 + 0) * 16][0]);
      GLOAD_LDS16(Bt + b_off1 + k0 + 32, &Bs[nxt][(i0 + 1) * 16][0]);
    }

    short8 a[4], b[4];
#pragma unroll
    for (int mi = 0; mi < 4; ++mi)
      a[mi] = *(const short8*)(&As[cur][wr + mi * 16 + lane16][quad * 8]);
#pragma unroll
    for (int ni = 0; ni < 4; ++ni)
      b[ni] = *(const short8*)(&Bs[cur][wc + ni * 16 + lane16][quad * 8]);
#pragma unroll
    for (int mi = 0; mi < 4; ++mi)
#pragma unroll
      for (int ni = 0; ni < 4; ++ni)
        acc[mi][ni] = __builtin_amdgcn_mfma_f32_16x16x32_bf16(
            a[mi], b[ni], acc[mi][ni], 0, 0, 0);
  }

#pragma unroll
  for (int ni = 0; ni < 4; ++ni) {
    const int col = n0 + wc + ni * 16 + lane16;
    const float bv = bias[col];
#pragma unroll
    for (int mi = 0; mi < 4; ++mi) {
      const int row = m0 + wr + mi * 16 + quad * 4;
#pragma unroll
      for (int r = 0; r < 4; ++r)
        store_out(&C[(size_t)(row + r) * N + col], acc[mi][ni][r] + bv);
    }
  }
}

// ---------------------------------------------------------------------------
// 256x192 bf16 GEMM (BK=64), grid-balanced (unchanged from round 4: 111 us,
// MfmaUtil 40%, 927 TF).
// ---------------------------------------------------------------------------
template <typename OutT>
__global__ __launch_bounds__(512, 2) void gemm_bf16_256x192(
    const unsigned short* __restrict__ A, const unsigned short* __restrict__ Bt,
    const float* __restrict__ bias, OutT* __restrict__ C,
    int M, int N, int K) {
  __shared__ __align__(16) unsigned short As[2][16384];  // 256x64
  __shared__ __align__(16) unsigned short Bs[2][12288];  // 192x64

  const int tid = threadIdx.x;
  const int w = tid >> 6;
  const int L = tid & 63;
  const int lane16 = L & 15;
  const int quad = L >> 4;
  const int wm = w >> 2;   // 0..1
  const int wn = w & 3;    // 0..3

  const int nby = M >> 8;          // 16
  const int q8 = gridDim.x >> 3;   // 64
  const int wg = (blockIdx.x & 7) * q8 + (blockIdx.x >> 3);
  const int by = wg % nby;
  const int bx = wg / nby;
  const int m0 = by << 8;
  const int n0 = bx * 192;

  const int lA = ((w >> 1) << 4) + (L >> 2);
  const int scol = ((w & 1) << 5) + (((L & 3) * 8) ^ ((L & 32) ? 16 : 0));
  unsigned aoff[4], boff[3];
#pragma unroll
  for (int j = 0; j < 4; ++j)
    aoff[j] = (unsigned)(m0 + j * 64 + lA) * (unsigned)K + scol;
#pragma unroll
  for (int j = 0; j < 3; ++j)
    boff[j] = (unsigned)(n0 + j * 64 + lA) * (unsigned)K + scol;
  const int ldst = w * 512;

  const int sq = (quad * 8) ^ ((lane16 & 8) << 1);
  const int rbase = lane16 * 32 + sq;

  floatx4 acc[8][3] = {};

  GLOAD_LDS16(A + aoff[0], &As[0][0 * 4096 + ldst]);
  GLOAD_LDS16(A + aoff[1], &As[0][1 * 4096 + ldst]);
  GLOAD_LDS16(A + aoff[2], &As[0][2 * 4096 + ldst]);
  GLOAD_LDS16(A + aoff[3], &As[0][3 * 4096 + ldst]);
  GLOAD_LDS16(Bt + boff[0], &Bs[0][0 * 4096 + ldst]);
  GLOAD_LDS16(Bt + boff[1], &Bs[0][1 * 4096 + ldst]);
  GLOAD_LDS16(Bt + boff[2], &Bs[0][2 * 4096 + ldst]);
  GLOAD_LDS16(Bt + boff[0] + 64, &Bs[1][0 * 4096 + ldst]);
  GLOAD_LDS16(Bt + boff[1] + 64, &Bs[1][1 * 4096 + ldst]);
  GLOAD_LDS16(Bt + boff[2] + 64, &Bs[1][2 * 4096 + ldst]);
  asm volatile("s_waitcnt vmcnt(3)" ::: "memory");
  __builtin_amdgcn_sched_barrier(0);
  __builtin_amdgcn_s_barrier();

  const int NT = K >> 6;  // 32
  short8 a[4][2], b[3][2];

  for (int t = 0; t < NT; ++t) {
    const int c = t & 1;
    const unsigned kn1 = (unsigned)(t + 1) << 6;
    const unsigned kn2 = (unsigned)(t + 2) << 6;
    const unsigned short* Ac = &As[c][0];
    const unsigned short* Bc = &Bs[c][0];

    // P0: read a-lo(8) + b(6); stage A(t+1); 24 MFMA
#pragma unroll
    for (int mi = 0; mi < 4; ++mi)
#pragma unroll
      for (int kk = 0; kk < 2; ++kk)
        a[mi][kk] = *(const short8*)(Ac + (wm * 2) * 4096 +
                                     ((mi * 2 + kk) * 512) + rbase);
#pragma unroll
    for (int ni = 0; ni < 3; ++ni) {
      const int f = wn * 3 + ni;
#pragma unroll
      for (int kk = 0; kk < 2; ++kk)
        b[ni][kk] = *(const short8*)(Bc + (f >> 2) * 4096 +
                                     (((f & 3) * 2 + kk) * 512) + rbase);
    }
    GLOAD_LDS16(A + aoff[0] + kn1, &As[c ^ 1][0 * 4096 + ldst]);
    GLOAD_LDS16(A + aoff[1] + kn1, &As[c ^ 1][1 * 4096 + ldst]);
    GLOAD_LDS16(A + aoff[2] + kn1, &As[c ^ 1][2 * 4096 + ldst]);
    GLOAD_LDS16(A + aoff[3] + kn1, &As[c ^ 1][3 * 4096 + ldst]);
    __builtin_amdgcn_s_setprio(1);
#pragma unroll
    for (int mi = 0; mi < 4; ++mi)
#pragma unroll
      for (int ni = 0; ni < 3; ++ni)
#pragma unroll
        for (int kk = 0; kk < 2; ++kk)
          acc[mi][ni] = __builtin_amdgcn_mfma_f32_16x16x32_bf16(
              a[mi][kk], b[ni][kk], acc[mi][ni], 0, 0, 0);
    __builtin_amdgcn_s_setprio(0);
    __builtin_amdgcn_sched_barrier(0);
    __builtin_amdgcn_s_barrier();

    // P1: read a-hi(8); stage B(t+2); 24 MFMA; vmcnt(3)
#pragma unroll
    for (int mi = 0; mi < 4; ++mi)
#pragma unroll
      for (int kk = 0; kk < 2; ++kk)
        a[mi][kk] = *(const short8*)(Ac + (wm * 2 + 1) * 4096 +
                                     ((mi * 2 + kk) * 512) + rbase);
    GLOAD_LDS16(Bt + boff[0] + kn2, &Bs[c][0 * 4096 + ldst]);
    GLOAD_LDS16(Bt + boff[1] + kn2, &Bs[c][1 * 4096 + ldst]);
    GLOAD_LDS16(Bt + boff[2] + kn2, &Bs[c][2 * 4096 + ldst]);
    __builtin_amdgcn_s_setprio(1);
#pragma unroll
    for (int mi = 0; mi < 4; ++mi)
#pragma unroll
      for (int ni = 0; ni < 3; ++ni)
#pragma unroll
        for (int kk = 0; kk < 2; ++kk)
          acc[4 + mi][ni] = __builtin_amdgcn_mfma_f32_16x16x32_bf16(
              a[mi][kk], b[ni][kk], acc[4 + mi][ni], 0, 0, 0);
    __builtin_amdgcn_s_setprio(0);
    asm volatile("s_waitcnt vmcnt(3)" ::: "memory");
    __builtin_amdgcn_sched_barrier(0);
    __builtin_amdgcn_s_barrier();
  }

  // epilogue
#pragma unroll
  for (int ni = 0; ni < 3; ++ni) {
    const int col = n0 + wn * 48 + ni * 16 + lane16;
    const float bv = bias[col];
#pragma unroll
    for (int mi = 0; mi < 8; ++mi) {
      const int row = m0 + wm * 128 + mi * 16 + quad * 4;
#pragma unroll
      for (int r = 0; r < 4; ++r)
        store_out(&C[(size_t)(row + r) * N + col], acc[mi][ni][r] + bv);
    }
  }
}

// ---------------------------------------------------------------------------
// Rotary on bf16 qkv in place. qkv layout [B][S][3][H][D] bf16.
// ---------------------------------------------------------------------------
__global__ __launch_bounds__(256) void rotary_kernel(unsigned short* __restrict__ qkv) {
  const int idx = blockIdx.x * blockDim.x + threadIdx.x;
  const int d = idx & 63;
  const int h = (idx >> 6) & (HH - 1);
  const int s = (idx >> 10) & (SS - 1);
  const int b = idx >> 21;

  const float inv_freq = __expf(-(float)d * 0.14391156509f);
  float sn, c;
  __sincosf((float)s * inv_freq, &sn, &c);

  const size_t base = ((size_t)b * SS + s) * FF + h * DD + d;
  unsigned short* q = qkv + base;
  unsigned short* k = qkv + base + EE;

  const float q1 = bf2f(q[0]), q2 = bf2f(q[64]);
  q[0]  = f2bf(q1 * c - q2 * sn);
  q[64] = f2bf(q2 * c + q1 * sn);
  const float k1 = bf2f(k[0]), k2 = bf2f(k[64]);
  k[0]  = f2bf(k1 * c - k2 * sn);
  k[64] = f2bf(k2 * c + k1 * sn);
}

// ---------------------------------------------------------------------------
// V transpose: qkv V slab [b][s][h][d] -> vt [b*H+h][d][s]   (bf16)
// ---------------------------------------------------------------------------
__global__ __launch_bounds__(256) void transpose_v(
    const unsigned short* __restrict__ qkv, unsigned short* __restrict__ vt) {
  __shared__ unsigned short T[64][72];
  const int t = threadIdx.x;
  const int s0 = blockIdx.x * 64;
  const int d0 = blockIdx.y * 64;
  const int bh = blockIdx.z;
  const int b = bh >> 4, h = bh & 15;
  {
    const int r = t >> 2, c = (t & 3) * 16;
    const unsigned short* src =
        qkv + ((size_t)b * SS + s0 + r) * FF + 2 * EE + h * DD + d0 + c;
    const uint4 u0 = *(const uint4*)src;
    const uint4 u1 = *(const uint4*)(src + 8);
    *(uint4*)&T[r][c] = u0;
    *(uint4*)&T[r][c + 8] = u1;
  }
  __syncthreads();
  {
    const int rr = t >> 2, cc = (t & 3) * 16;
    unsigned short vals[16];
#pragma unroll
    for (int j = 0; j < 16; ++j) vals[j] = T[cc + j][rr];
    unsigned short* dst =
        vt + (size_t)bh * DD * SS + (size_t)(d0 + rr) * SS + s0 + cc;
    *(uint4*)dst = *(uint4*)&vals[0];
    *(uint4*)(dst + 8) = *(uint4*)&vals[8];
  }
}

// ---------------------------------------------------------------------------
// MFMA flash attention, causal. This round: ONE q-tile per block (grid 512 =
// 2 blocks/CU, double occupancy vs the paired 256-block version whose
// counters showed Occupancy 10.9% / MfmaUtil 12.5% / VALUBusy 29.5% -- pure
// latency-bound at 1 wave/SIMD). Heavy tiles dispatch first (LPT): qb = 15 -
// (flat>>5); bh = flat&31 keeps flat%8 const per bh -> all 16 blocks of one
// (b,h) K/V stream on one XCD (4 streams x 1MB per XCD L2). T13 defer-max:
// skip O-rescale when __all(tm - m <= 8) (P bounded by e^8, bf16-safe).
// ---------------------------------------------------------------------------
#define ATQ 128
#define ATK 32
#define SPAD 40
#define NQT (SS / ATQ)

__global__ __launch_bounds__(256, 2) void attn_mfma(
    const unsigned short* __restrict__ qkv,
    const unsigned short* __restrict__ vt,
    unsigned short* __restrict__ ctx) {
  __shared__ __align__(16) unsigned short Ksh[2][ATK * DD];
  __shared__ __align__(16) unsigned short Vsh[2][DD * ATK];
  __shared__ __align__(16) unsigned short Ssh[ATQ][SPAD];

  const int tid = threadIdx.x;
  const int L = tid & 63;
  const int w = tid >> 6;
  const int lane16 = L & 15;
  const int quad = L >> 4;

  const int flat = blockIdx.x;        // 0..511
  const int bh_lin = flat & 31;       // fastest -> flat%8 const per bh
  const int qb = (NQT - 1) - (flat >> 5);  // heavy q-tiles first (LPT)
  const int b = bh_lin >> 4;
  const int h = bh_lin & 15;
  const int bh = b * HH + h;
  const float scale = 0.08838834764831845f;

  size_t koff[2], voff[2];
  int kdst[2], vdst[2];
#pragma unroll
  for (int j = 0; j < 2; ++j) {
    const int ck = j * 256 + tid;
    const int kk = ck >> 4;
    const int cgk = (ck & 15) ^ (kk & 15);
    koff[j] = ((size_t)b * SS + kk) * FF + EE + h * DD + cgk * 8;
    kdst[j] = (j * 256 + w * 64) * 8;
    const int d = ck >> 2;
    const int cgv = (ck & 3) ^ (d & 3);
    voff[j] = (size_t)bh * DD * SS + (size_t)d * SS + cgv * 8;
    vdst[j] = kdst[j];
  }

  const int q0 = qb * ATQ;

  // Q frags (B-operand)
  short8 qf[2][4];
#pragma unroll
  for (int mi = 0; mi < 2; ++mi) {
    const int q = q0 + w * 32 + mi * 16 + lane16;
    const unsigned short* qp =
        qkv + ((size_t)b * SS + q) * FF + h * DD + quad * 8;
#pragma unroll
    for (int dc = 0; dc < 4; ++dc)
      qf[mi][dc] = *(const short8*)(qp + dc * 32);
  }

  floatx4 acc[8][2] = {};
  float m_i[2] = {-3.0e38f, -3.0e38f};
  float l_i[2] = {0.0f, 0.0f};

  const int nkt = 4 * qb + 4;
  const int mykt = 4 * qb + w;

  // prologue: stage tile 0 -> buf 0
#pragma unroll
  for (int j = 0; j < 2; ++j) {
    GLOAD_LDS16(qkv + koff[j], &Ksh[0][kdst[j]]);
    GLOAD_LDS16(vt + voff[j], &Vsh[0][vdst[j]]);
  }

  for (int kt = 0; kt < nkt; ++kt) {
    const int cur = kt & 1;
    __syncthreads();  // drains stage(kt)
    if (kt + 1 < nkt) {
      const size_t ka = (size_t)(kt + 1) * ATK * FF;
      const int va = (kt + 1) * ATK;
#pragma unroll
      for (int j = 0; j < 2; ++j) {
        GLOAD_LDS16(qkv + koff[j] + ka, &Ksh[cur ^ 1][kdst[j]]);
        GLOAD_LDS16(vt + voff[j] + va, &Vsh[cur ^ 1][vdst[j]]);
      }
    }
    if (kt > mykt) continue;  // fully-masked diagonal tile for this wave
    const int k0 = kt * ATK;
    const unsigned short* Kc = Ksh[cur];
    const unsigned short* Vc = Vsh[cur];

    // --- S^T = K x Q^T ---
    floatx4 st[2][2] = {};
    __builtin_amdgcn_s_setprio(1);
#pragma unroll
    for (int kkt = 0; kkt < 2; ++kkt) {
      const unsigned short* krow = Kc + (kkt * 16 + lane16) * 128;
#pragma unroll
      for (int dc = 0; dc < 4; ++dc) {
        const short8 kf =
            *(const short8*)(krow + ((dc * 4 + quad) ^ lane16) * 8);
#pragma unroll
        for (int mi = 0; mi < 2; ++mi)
          st[kkt][mi] = __builtin_amdgcn_mfma_f32_16x16x32_bf16(
              kf, qf[mi][dc], st[kkt][mi], 0, 0, 0);
      }
    }
    __builtin_amdgcn_s_setprio(0);

    // --- scale + causal mask (diagonal tile only) ---
    const bool needmask = (kt == mykt);
#pragma unroll
    for (int mi = 0; mi < 2; ++mi) {
      const int q_glob = q0 + w * 32 + mi * 16 + lane16;
#pragma unroll
      for (int kkt = 0; kkt < 2; ++kkt) {
        const int kkb = k0 + kkt * 16 + quad * 4;
#pragma unroll
        for (int r = 0; r < 4; ++r) {
          float v = st[kkt][mi][r] * scale;
          if (needmask && (kkb + r) > q_glob) v = -3.0e38f;
          st[kkt][mi][r] = v;
        }
      }
    }

    // --- online softmax with T13 defer-max ---
#pragma unroll
    for (int mi = 0; mi < 2; ++mi) {
      float tm = -3.0e38f;
#pragma unroll
      for (int kkt = 0; kkt < 2; ++kkt)
#pragma unroll
        for (int r = 0; r < 4; ++r) tm = fmaxf(tm, st[kkt][mi][r]);
      tm = fmaxf(tm, __shfl_xor(tm, 16));
      tm = fmaxf(tm, __shfl_xor(tm, 32));

      const bool need = !__all(tm - m_i[mi] <= 8.0f);
      if (need) {
        const float mn = fmaxf(m_i[mi], tm);
        const float alpha = __expf(m_i[mi] - mn);
        m_i[mi] = mn;
        l_i[mi] *= alpha;
#pragma unroll
        for (int dt = 0; dt < 8; ++dt)
#pragma unroll
          for (int r = 0; r < 4; ++r) acc[dt][mi][r] *= alpha;
      }

      float rs = 0.0f;
#pragma unroll
      for (int kkt = 0; kkt < 2; ++kkt)
#pragma unroll
        for (int r = 0; r < 4; ++r) {
          const float p = __expf(st[kkt][mi][r] - m_i[mi]);
          st[kkt][mi][r] = p;
          rs += p;
        }
      rs += __shfl_xor(rs, 16);
      rs += __shfl_xor(rs, 32);
      l_i[mi] += rs;

#pragma unroll
      for (int kkt = 0; kkt < 2; ++kkt) {
        ushort4 pk;
        pk.x = f2bf(st[kkt][mi][0]);
        pk.y = f2bf(st[kkt][mi][1]);
        pk.z = f2bf(st[kkt][mi][2]);
        pk.w = f2bf(st[kkt][mi][3]);
        *(ushort4*)(&Ssh[w * 32 + mi * 16 + lane16][kkt * 16 + quad * 4]) = pk;
      }
    }

    // --- O^T += V^T x P^T ---
    short8 pa[2];
#pragma unroll
    for (int mi = 0; mi < 2; ++mi)
      pa[mi] = *(const short8*)(&Ssh[w * 32 + mi * 16 + lane16][quad * 8]);
    const int vpos = (quad ^ (lane16 & 3)) * 8;
    __builtin_amdgcn_s_setprio(1);
#pragma unroll
    for (int dt = 0; dt < 8; ++dt) {
      const short8 vf = *(const short8*)(Vc + (dt * 16 + lane16) * 32 + vpos);
#pragma unroll
      for (int mi = 0; mi < 2; ++mi)
        acc[dt][mi] = __builtin_amdgcn_mfma_f32_16x16x32_bf16(
            vf, pa[mi], acc[dt][mi], 0, 0, 0);
    }
    __builtin_amdgcn_s_setprio(0);
  }

  // epilogue
#pragma unroll
  for (int mi = 0; mi < 2; ++mi) {
    const float inv = 1.0f / l_i[mi];
    const int q = q0 + w * 32 + mi * 16 + lane16;
    unsigned short* op = ctx + ((size_t)b * SS + q) * EE + h * DD + quad * 4;
#pragma unroll
    for (int dt = 0; dt < 8; ++dt) {
      ushort4 o;
      o.x = f2bf(acc[dt][mi][0] * inv);
      o.y = f2bf(acc[dt][mi][1] * inv);
      o.z = f2bf(acc[dt][mi][2] * inv);
      o.w = f2bf(acc[dt][mi][3] * inv);
      *(ushort4*)(op + dt * 16) = o;
    }
  }
}

// ---------------------------------------------------------------------------
// Launch
// ---------------------------------------------------------------------------
extern "C" void kernel_launch(void* const* d_in, const int* in_sizes, int n_in,
                              void* d_out, int out_size, void* d_ws,
                              size_t ws_size, hipStream_t stream) {
  const float* x    = (const float*)d_in[0];
  const float* wqkv = (const float*)d_in[1];
  const float* bqkv = (const float*)d_in[2];
  const float* wout = (const float*)d_in[3];
  const float* bout = (const float*)d_in[4];
  float* out = (float*)d_out;

  unsigned short* qkvb = (unsigned short*)d_ws;      // 25165824 elems
  unsigned short* xb   = qkvb + (size_t)25165824;    //  8388608
  unsigned short* wqb  = xb + (size_t)8388608;       // 12582912
  unsigned short* ctxb = wqb + (size_t)12582912;     //  8388608
  unsigned short* wob  = ctxb + (size_t)8388608;     //  4194304
  unsigned short* vtb  = wob + (size_t)4194304;      //  8388608

  const int M = BB * SS;  // 4096

  cast_f32_bf16<<<8192, 256, 0, stream>>>(x, xb, 2097152);
  cast_f32_bf16<<<12288, 256, 0, stream>>>(wqkv, wqb, 3145728);
  cast_f32_bf16<<<4096, 256, 0, stream>>>(wout, wob, 1048576);

  {
    // 256x192 balanced grid: 16 x 32 = 512 blocks = exactly 2 rounds
    gemm_bf16_256x192<unsigned short><<<dim3(512), 512, 0, stream>>>(
        xb, wqb, bqkv, qkvb, M, FF, EE);
  }
  {
    const int total = BB * SS * HH * 64;
    rotary_kernel<<<total / 256, 256, 0, stream>>>(qkvb);
  }
  {
    dim3 grid(SS / 64, DD / 64, BB * HH);
    transpose_v<<<grid, 256, 0, stream>>>(qkvb, vtb);
  }
  {
    // one q-tile per block: 512 blocks = 2 blocks/CU, heavy tiles first
    attn_mfma<<<dim3(512), 256, 0, stream>>>(qkvb, vtb, ctxb);
  }
  {
    dim3 grid(EE / 128, M / 128);
    gemm_bf16_mfma<float><<<grid, 256, 0, stream>>>(
        ctxb, wob, bout, out, M, EE, EE);
  }
}

// Round 6
// 398.259 us; speedup vs baseline: 1.0543x; 1.0543x over previous
//
#include <hip/hip_runtime.h>
#include <math.h>

// Problem constants
#define BB 2
#define SS 2048
#define EE 2048
#define HH 16
#define DD 128
#define FF 6144   // 3*E

typedef __attribute__((ext_vector_type(8))) short short8;
typedef __attribute__((ext_vector_type(4))) float floatx4;

static __device__ __forceinline__ unsigned short f2bf(float x) {
  unsigned u = __float_as_uint(x);
  u += 0x7fffu + ((u >> 16) & 1u);
  return (unsigned short)(u >> 16);
}
static __device__ __forceinline__ float bf2f(unsigned short h) {
  return __uint_as_float((unsigned)h << 16);
}

#define GLOAD_LDS16(gp, lp)                                       \
  __builtin_amdgcn_global_load_lds(                               \
      (const __attribute__((address_space(1))) void*)(gp),        \
      (__attribute__((address_space(3))) void*)(lp), 16, 0, 0)

// ---------------------------------------------------------------------------
// fp32 -> bf16 cast (float4 in, ushort4 out)
// ---------------------------------------------------------------------------
__global__ __launch_bounds__(256) void cast_f32_bf16(
    const float* __restrict__ in, unsigned short* __restrict__ out, int n4) {
  const int i = blockIdx.x * 256 + threadIdx.x;
  if (i >= n4) return;
  const float4 v = ((const float4*)in)[i];
  ushort4 o;
  o.x = f2bf(v.x); o.y = f2bf(v.y); o.z = f2bf(v.z); o.w = f2bf(v.w);
  ((ushort4*)out)[i] = o;
}

static __device__ __forceinline__ void store_out(float* p, float v) { *p = v; }
static __device__ __forceinline__ void store_out(unsigned short* p, float v) {
  *p = f2bf(v);
}

// ---------------------------------------------------------------------------
// 256x192 bf16 GEMM (BK=64), grid-balanced (unchanged from round 4: 111 us,
// MfmaUtil 40%, 927 TF). Used for QKV (N=6144).
// ---------------------------------------------------------------------------
template <typename OutT>
__global__ __launch_bounds__(512, 2) void gemm_bf16_256x192(
    const unsigned short* __restrict__ A, const unsigned short* __restrict__ Bt,
    const float* __restrict__ bias, OutT* __restrict__ C,
    int M, int N, int K) {
  __shared__ __align__(16) unsigned short As[2][16384];  // 256x64
  __shared__ __align__(16) unsigned short Bs[2][12288];  // 192x64

  const int tid = threadIdx.x;
  const int w = tid >> 6;
  const int L = tid & 63;
  const int lane16 = L & 15;
  const int quad = L >> 4;
  const int wm = w >> 2;   // 0..1
  const int wn = w & 3;    // 0..3

  const int nby = M >> 8;          // 16
  const int q8 = gridDim.x >> 3;   // 64
  const int wg = (blockIdx.x & 7) * q8 + (blockIdx.x >> 3);
  const int by = wg % nby;
  const int bx = wg / nby;
  const int m0 = by << 8;
  const int n0 = bx * 192;

  const int lA = ((w >> 1) << 4) + (L >> 2);
  const int scol = ((w & 1) << 5) + (((L & 3) * 8) ^ ((L & 32) ? 16 : 0));
  unsigned aoff[4], boff[3];
#pragma unroll
  for (int j = 0; j < 4; ++j)
    aoff[j] = (unsigned)(m0 + j * 64 + lA) * (unsigned)K + scol;
#pragma unroll
  for (int j = 0; j < 3; ++j)
    boff[j] = (unsigned)(n0 + j * 64 + lA) * (unsigned)K + scol;
  const int ldst = w * 512;

  const int sq = (quad * 8) ^ ((lane16 & 8) << 1);
  const int rbase = lane16 * 32 + sq;

  floatx4 acc[8][3] = {};

  GLOAD_LDS16(A + aoff[0], &As[0][0 * 4096 + ldst]);
  GLOAD_LDS16(A + aoff[1], &As[0][1 * 4096 + ldst]);
  GLOAD_LDS16(A + aoff[2], &As[0][2 * 4096 + ldst]);
  GLOAD_LDS16(A + aoff[3], &As[0][3 * 4096 + ldst]);
  GLOAD_LDS16(Bt + boff[0], &Bs[0][0 * 4096 + ldst]);
  GLOAD_LDS16(Bt + boff[1], &Bs[0][1 * 4096 + ldst]);
  GLOAD_LDS16(Bt + boff[2], &Bs[0][2 * 4096 + ldst]);
  GLOAD_LDS16(Bt + boff[0] + 64, &Bs[1][0 * 4096 + ldst]);
  GLOAD_LDS16(Bt + boff[1] + 64, &Bs[1][1 * 4096 + ldst]);
  GLOAD_LDS16(Bt + boff[2] + 64, &Bs[1][2 * 4096 + ldst]);
  asm volatile("s_waitcnt vmcnt(3)" ::: "memory");
  __builtin_amdgcn_sched_barrier(0);
  __builtin_amdgcn_s_barrier();

  const int NT = K >> 6;  // 32
  short8 a[4][2], b[3][2];

  for (int t = 0; t < NT; ++t) {
    const int c = t & 1;
    const unsigned kn1 = (unsigned)(t + 1) << 6;
    const unsigned kn2 = (unsigned)(t + 2) << 6;
    const unsigned short* Ac = &As[c][0];
    const unsigned short* Bc = &Bs[c][0];

    // P0: read a-lo(8) + b(6); stage A(t+1); 24 MFMA
#pragma unroll
    for (int mi = 0; mi < 4; ++mi)
#pragma unroll
      for (int kk = 0; kk < 2; ++kk)
        a[mi][kk] = *(const short8*)(Ac + (wm * 2) * 4096 +
                                     ((mi * 2 + kk) * 512) + rbase);
#pragma unroll
    for (int ni = 0; ni < 3; ++ni) {
      const int f = wn * 3 + ni;
#pragma unroll
      for (int kk = 0; kk < 2; ++kk)
        b[ni][kk] = *(const short8*)(Bc + (f >> 2) * 4096 +
                                     (((f & 3) * 2 + kk) * 512) + rbase);
    }
    GLOAD_LDS16(A + aoff[0] + kn1, &As[c ^ 1][0 * 4096 + ldst]);
    GLOAD_LDS16(A + aoff[1] + kn1, &As[c ^ 1][1 * 4096 + ldst]);
    GLOAD_LDS16(A + aoff[2] + kn1, &As[c ^ 1][2 * 4096 + ldst]);
    GLOAD_LDS16(A + aoff[3] + kn1, &As[c ^ 1][3 * 4096 + ldst]);
    __builtin_amdgcn_s_setprio(1);
#pragma unroll
    for (int mi = 0; mi < 4; ++mi)
#pragma unroll
      for (int ni = 0; ni < 3; ++ni)
#pragma unroll
        for (int kk = 0; kk < 2; ++kk)
          acc[mi][ni] = __builtin_amdgcn_mfma_f32_16x16x32_bf16(
              a[mi][kk], b[ni][kk], acc[mi][ni], 0, 0, 0);
    __builtin_amdgcn_s_setprio(0);
    __builtin_amdgcn_sched_barrier(0);
    __builtin_amdgcn_s_barrier();

    // P1: read a-hi(8); stage B(t+2); 24 MFMA; vmcnt(3)
#pragma unroll
    for (int mi = 0; mi < 4; ++mi)
#pragma unroll
      for (int kk = 0; kk < 2; ++kk)
        a[mi][kk] = *(const short8*)(Ac + (wm * 2 + 1) * 4096 +
                                     ((mi * 2 + kk) * 512) + rbase);
    GLOAD_LDS16(Bt + boff[0] + kn2, &Bs[c][0 * 4096 + ldst]);
    GLOAD_LDS16(Bt + boff[1] + kn2, &Bs[c][1 * 4096 + ldst]);
    GLOAD_LDS16(Bt + boff[2] + kn2, &Bs[c][2 * 4096 + ldst]);
    __builtin_amdgcn_s_setprio(1);
#pragma unroll
    for (int mi = 0; mi < 4; ++mi)
#pragma unroll
      for (int ni = 0; ni < 3; ++ni)
#pragma unroll
        for (int kk = 0; kk < 2; ++kk)
          acc[4 + mi][ni] = __builtin_amdgcn_mfma_f32_16x16x32_bf16(
              a[mi][kk], b[ni][kk], acc[4 + mi][ni], 0, 0, 0);
    __builtin_amdgcn_s_setprio(0);
    asm volatile("s_waitcnt vmcnt(3)" ::: "memory");
    __builtin_amdgcn_sched_barrier(0);
    __builtin_amdgcn_s_barrier();
  }

  // epilogue
#pragma unroll
  for (int ni = 0; ni < 3; ++ni) {
    const int col = n0 + wn * 48 + ni * 16 + lane16;
    const float bv = bias[col];
#pragma unroll
    for (int mi = 0; mi < 8; ++mi) {
      const int row = m0 + wm * 128 + mi * 16 + quad * 4;
#pragma unroll
      for (int r = 0; r < 4; ++r)
        store_out(&C[(size_t)(row + r) * N + col], acc[mi][ni][r] + bv);
    }
  }
}

// ---------------------------------------------------------------------------
// 256x128 bf16 GEMM (BK=64): same verified 2-phase template, parameterized
// for the out-projection N=2048: grid 16x16 = 256 blocks = exactly 1 round.
// Per-wave C = 128x32 (acc 64 VGPR). LDS 96 KiB -> 1 block/CU.
// P0: read a-lo(8)+b(4); stage A(t+1)(4); 16 MFMA
// P1: read a-hi(8);      stage B(t+2)(2); 16 MFMA; vmcnt(2)
// ---------------------------------------------------------------------------
template <typename OutT>
__global__ __launch_bounds__(512, 2) void gemm_bf16_256x128(
    const unsigned short* __restrict__ A, const unsigned short* __restrict__ Bt,
    const float* __restrict__ bias, OutT* __restrict__ C,
    int M, int N, int K) {
  __shared__ __align__(16) unsigned short As[2][16384];  // 256x64
  __shared__ __align__(16) unsigned short Bs[2][8192];   // 128x64

  const int tid = threadIdx.x;
  const int w = tid >> 6;
  const int L = tid & 63;
  const int lane16 = L & 15;
  const int quad = L >> 4;
  const int wm = w >> 2;   // 0..1
  const int wn = w & 3;    // 0..3

  const int nby = M >> 8;          // 16
  const int q8 = gridDim.x >> 3;   // 32
  const int wg = (blockIdx.x & 7) * q8 + (blockIdx.x >> 3);
  const int by = wg % nby;
  const int bx = wg / nby;
  const int m0 = by << 8;
  const int n0 = bx << 7;

  const int lA = ((w >> 1) << 4) + (L >> 2);
  const int scol = ((w & 1) << 5) + (((L & 3) * 8) ^ ((L & 32) ? 16 : 0));
  unsigned aoff[4], boff[2];
#pragma unroll
  for (int j = 0; j < 4; ++j)
    aoff[j] = (unsigned)(m0 + j * 64 + lA) * (unsigned)K + scol;
#pragma unroll
  for (int j = 0; j < 2; ++j)
    boff[j] = (unsigned)(n0 + j * 64 + lA) * (unsigned)K + scol;
  const int ldst = w * 512;

  const int sq = (quad * 8) ^ ((lane16 & 8) << 1);
  const int rbase = lane16 * 32 + sq;

  floatx4 acc[8][2] = {};

  GLOAD_LDS16(A + aoff[0], &As[0][0 * 4096 + ldst]);
  GLOAD_LDS16(A + aoff[1], &As[0][1 * 4096 + ldst]);
  GLOAD_LDS16(A + aoff[2], &As[0][2 * 4096 + ldst]);
  GLOAD_LDS16(A + aoff[3], &As[0][3 * 4096 + ldst]);
  GLOAD_LDS16(Bt + boff[0], &Bs[0][0 * 4096 + ldst]);
  GLOAD_LDS16(Bt + boff[1], &Bs[0][1 * 4096 + ldst]);
  GLOAD_LDS16(Bt + boff[0] + 64, &Bs[1][0 * 4096 + ldst]);
  GLOAD_LDS16(Bt + boff[1] + 64, &Bs[1][1 * 4096 + ldst]);
  asm volatile("s_waitcnt vmcnt(2)" ::: "memory");
  __builtin_amdgcn_sched_barrier(0);
  __builtin_amdgcn_s_barrier();

  const int NT = K >> 6;  // 32
  short8 a[4][2], b[2][2];

  for (int t = 0; t < NT; ++t) {
    const int c = t & 1;
    const unsigned kn1 = (unsigned)(t + 1) << 6;
    const unsigned kn2 = (unsigned)(t + 2) << 6;
    const unsigned short* Ac = &As[c][0];
    const unsigned short* Bc = &Bs[c][0];

    // P0: read a-lo(8) + b(4); stage A(t+1); 16 MFMA
#pragma unroll
    for (int mi = 0; mi < 4; ++mi)
#pragma unroll
      for (int kk = 0; kk < 2; ++kk)
        a[mi][kk] = *(const short8*)(Ac + (wm * 2) * 4096 +
                                     ((mi * 2 + kk) * 512) + rbase);
#pragma unroll
    for (int ni = 0; ni < 2; ++ni) {
      const int f = wn * 2 + ni;
#pragma unroll
      for (int kk = 0; kk < 2; ++kk)
        b[ni][kk] = *(const short8*)(Bc + (f >> 2) * 4096 +
                                     (((f & 3) * 2 + kk) * 512) + rbase);
    }
    GLOAD_LDS16(A + aoff[0] + kn1, &As[c ^ 1][0 * 4096 + ldst]);
    GLOAD_LDS16(A + aoff[1] + kn1, &As[c ^ 1][1 * 4096 + ldst]);
    GLOAD_LDS16(A + aoff[2] + kn1, &As[c ^ 1][2 * 4096 + ldst]);
    GLOAD_LDS16(A + aoff[3] + kn1, &As[c ^ 1][3 * 4096 + ldst]);
    __builtin_amdgcn_s_setprio(1);
#pragma unroll
    for (int mi = 0; mi < 4; ++mi)
#pragma unroll
      for (int ni = 0; ni < 2; ++ni)
#pragma unroll
        for (int kk = 0; kk < 2; ++kk)
          acc[mi][ni] = __builtin_amdgcn_mfma_f32_16x16x32_bf16(
              a[mi][kk], b[ni][kk], acc[mi][ni], 0, 0, 0);
    __builtin_amdgcn_s_setprio(0);
    __builtin_amdgcn_sched_barrier(0);
    __builtin_amdgcn_s_barrier();

    // P1: read a-hi(8); stage B(t+2); 16 MFMA; vmcnt(2)
#pragma unroll
    for (int mi = 0; mi < 4; ++mi)
#pragma unroll
      for (int kk = 0; kk < 2; ++kk)
        a[mi][kk] = *(const short8*)(Ac + (wm * 2 + 1) * 4096 +
                                     ((mi * 2 + kk) * 512) + rbase);
    GLOAD_LDS16(Bt + boff[0] + kn2, &Bs[c][0 * 4096 + ldst]);
    GLOAD_LDS16(Bt + boff[1] + kn2, &Bs[c][1 * 4096 + ldst]);
    __builtin_amdgcn_s_setprio(1);
#pragma unroll
    for (int mi = 0; mi < 4; ++mi)
#pragma unroll
      for (int ni = 0; ni < 2; ++ni)
#pragma unroll
        for (int kk = 0; kk < 2; ++kk)
          acc[4 + mi][ni] = __builtin_amdgcn_mfma_f32_16x16x32_bf16(
              a[mi][kk], b[ni][kk], acc[4 + mi][ni], 0, 0, 0);
    __builtin_amdgcn_s_setprio(0);
    asm volatile("s_waitcnt vmcnt(2)" ::: "memory");
    __builtin_amdgcn_sched_barrier(0);
    __builtin_amdgcn_s_barrier();
  }

  // epilogue
#pragma unroll
  for (int ni = 0; ni < 2; ++ni) {
    const int col = n0 + wn * 32 + ni * 16 + lane16;
    const float bv = bias[col];
#pragma unroll
    for (int mi = 0; mi < 8; ++mi) {
      const int row = m0 + wm * 128 + mi * 16 + quad * 4;
#pragma unroll
      for (int r = 0; r < 4; ++r)
        store_out(&C[(size_t)(row + r) * N + col], acc[mi][ni][r] + bv);
    }
  }
}

// ---------------------------------------------------------------------------
// Rotary on bf16 qkv in place. qkv layout [B][S][3][H][D] bf16.
// ---------------------------------------------------------------------------
__global__ __launch_bounds__(256) void rotary_kernel(unsigned short* __restrict__ qkv) {
  const int idx = blockIdx.x * blockDim.x + threadIdx.x;
  const int d = idx & 63;
  const int h = (idx >> 6) & (HH - 1);
  const int s = (idx >> 10) & (SS - 1);
  const int b = idx >> 21;

  const float inv_freq = __expf(-(float)d * 0.14391156509f);
  float sn, c;
  __sincosf((float)s * inv_freq, &sn, &c);

  const size_t base = ((size_t)b * SS + s) * FF + h * DD + d;
  unsigned short* q = qkv + base;
  unsigned short* k = qkv + base + EE;

  const float q1 = bf2f(q[0]), q2 = bf2f(q[64]);
  q[0]  = f2bf(q1 * c - q2 * sn);
  q[64] = f2bf(q2 * c + q1 * sn);
  const float k1 = bf2f(k[0]), k2 = bf2f(k[64]);
  k[0]  = f2bf(k1 * c - k2 * sn);
  k[64] = f2bf(k2 * c + k1 * sn);
}

// ---------------------------------------------------------------------------
// V transpose: qkv V slab [b][s][h][d] -> vt [b*H+h][d][s]   (bf16)
// ---------------------------------------------------------------------------
__global__ __launch_bounds__(256) void transpose_v(
    const unsigned short* __restrict__ qkv, unsigned short* __restrict__ vt) {
  __shared__ unsigned short T[64][72];
  const int t = threadIdx.x;
  const int s0 = blockIdx.x * 64;
  const int d0 = blockIdx.y * 64;
  const int bh = blockIdx.z;
  const int b = bh >> 4, h = bh & 15;
  {
    const int r = t >> 2, c = (t & 3) * 16;
    const unsigned short* src =
        qkv + ((size_t)b * SS + s0 + r) * FF + 2 * EE + h * DD + d0 + c;
    const uint4 u0 = *(const uint4*)src;
    const uint4 u1 = *(const uint4*)(src + 8);
    *(uint4*)&T[r][c] = u0;
    *(uint4*)&T[r][c + 8] = u1;
  }
  __syncthreads();
  {
    const int rr = t >> 2, cc = (t & 3) * 16;
    unsigned short vals[16];
#pragma unroll
    for (int j = 0; j < 16; ++j) vals[j] = T[cc + j][rr];
    unsigned short* dst =
        vt + (size_t)bh * DD * SS + (size_t)(d0 + rr) * SS + s0 + cc;
    *(uint4*)dst = *(uint4*)&vals[0];
    *(uint4*)(dst + 8) = *(uint4*)&vals[8];
  }
}

// ---------------------------------------------------------------------------
// MFMA flash attention, causal. This round: 8 WAVES per block (512 thr),
// each wave owns 16 q-rows (was 4 waves x 32 rows). Halves the per-block
// serial chain per kt (half the MFMAs, softmax elems, LDS reads per wave) --
// the r5 lesson: makespan = critical path of the longest block (qb=15), so
// the chain itself must shrink. Staging becomes exactly 1 K + 1 V gload_lds
// per thread (512 x 16B = 8KB tile). 2 blocks/CU (43KB LDS) = 4 waves/SIMD.
// LPT (heavy qb first) + XCD co-location + T13 defer-max kept.
// ---------------------------------------------------------------------------
#define ATQ 128
#define ATK 32
#define SPAD 40
#define NQT (SS / ATQ)

__global__ __launch_bounds__(512, 4) void attn_mfma(
    const unsigned short* __restrict__ qkv,
    const unsigned short* __restrict__ vt,
    unsigned short* __restrict__ ctx) {
  __shared__ __align__(16) unsigned short Ksh[2][ATK * DD];
  __shared__ __align__(16) unsigned short Vsh[2][DD * ATK];
  __shared__ __align__(16) unsigned short Ssh[ATQ][SPAD];

  const int tid = threadIdx.x;
  const int L = tid & 63;
  const int w = tid >> 6;          // 0..7
  const int lane16 = L & 15;
  const int quad = L >> 4;

  const int flat = blockIdx.x;        // 0..511
  const int bh_lin = flat & 31;       // fastest -> flat%8 const per bh
  const int qb = (NQT - 1) - (flat >> 5);  // heavy q-tiles first (LPT)
  const int b = bh_lin >> 4;
  const int h = bh_lin & 15;
  const int bh = b * HH + h;
  const float scale = 0.08838834764831845f;

  // Staging: one K-row-slice and one V-row-slice per thread (8KB each tile).
  const int kkrow = tid >> 4;                       // 0..31
  const int cgk = (tid & 15) ^ (kkrow & 15);
  const size_t koff =
      ((size_t)b * SS + kkrow) * FF + EE + h * DD + cgk * 8;
  const int drow = tid >> 2;                        // 0..127
  const int cgv = (tid & 3) ^ (drow & 3);
  const size_t voff = (size_t)bh * DD * SS + (size_t)drow * SS + cgv * 8;
  const int dstKV = w * 512;  // wave-uniform LDS dest (ushorts)

  const int q0 = qb * ATQ;

  // Q frags (B-operand): wave w owns rows q0 + w*16 + lane16
  short8 qf[4];
  {
    const int q = q0 + w * 16 + lane16;
    const unsigned short* qp =
        qkv + ((size_t)b * SS + q) * FF + h * DD + quad * 8;
#pragma unroll
    for (int dc = 0; dc < 4; ++dc) qf[dc] = *(const short8*)(qp + dc * 32);
  }

  floatx4 acc[8] = {};
  float m_i = -3.0e38f;
  float l_i = 0.0f;

  const int nkt = 4 * qb + 4;
  const int mykt = 4 * qb + (w >> 1);

  // prologue: stage tile 0 -> buf 0
  GLOAD_LDS16(qkv + koff, &Ksh[0][dstKV]);
  GLOAD_LDS16(vt + voff, &Vsh[0][dstKV]);

  for (int kt = 0; kt < nkt; ++kt) {
    const int cur = kt & 1;
    __syncthreads();  // drains stage(kt)
    if (kt + 1 < nkt) {
      const size_t ka = (size_t)(kt + 1) * ATK * FF;
      const int va = (kt + 1) * ATK;
      GLOAD_LDS16(qkv + koff + ka, &Ksh[cur ^ 1][dstKV]);
      GLOAD_LDS16(vt + voff + va, &Vsh[cur ^ 1][dstKV]);
    }
    if (kt > mykt) continue;  // fully-masked tile for this wave
    const int k0 = kt * ATK;
    const unsigned short* Kc = Ksh[cur];
    const unsigned short* Vc = Vsh[cur];

    // --- S^T = K x Q^T : 32 kk x 16 q per wave ---
    floatx4 st[2] = {};
    __builtin_amdgcn_s_setprio(1);
#pragma unroll
    for (int kkt = 0; kkt < 2; ++kkt) {
      const unsigned short* krow = Kc + (kkt * 16 + lane16) * 128;
#pragma unroll
      for (int dc = 0; dc < 4; ++dc) {
        const short8 kf =
            *(const short8*)(krow + ((dc * 4 + quad) ^ lane16) * 8);
        st[kkt] = __builtin_amdgcn_mfma_f32_16x16x32_bf16(
            kf, qf[dc], st[kkt], 0, 0, 0);
      }
    }
    __builtin_amdgcn_s_setprio(0);

    // --- scale + causal mask (diagonal tile only) ---
    const bool needmask = (kt == mykt);
    const int q_glob = q0 + w * 16 + lane16;
#pragma unroll
    for (int kkt = 0; kkt < 2; ++kkt) {
      const int kkb = k0 + kkt * 16 + quad * 4;
#pragma unroll
      for (int r = 0; r < 4; ++r) {
        float v = st[kkt][r] * scale;
        if (needmask && (kkb + r) > q_glob) v = -3.0e38f;
        st[kkt][r] = v;
      }
    }

    // --- online softmax (T13 defer-max) ---
    {
      float tm = -3.0e38f;
#pragma unroll
      for (int kkt = 0; kkt < 2; ++kkt)
#pragma unroll
        for (int r = 0; r < 4; ++r) tm = fmaxf(tm, st[kkt][r]);
      tm = fmaxf(tm, __shfl_xor(tm, 16));
      tm = fmaxf(tm, __shfl_xor(tm, 32));

      const bool need = !__all(tm - m_i <= 8.0f);
      if (need) {
        const float mn = fmaxf(m_i, tm);
        const float alpha = __expf(m_i - mn);
        m_i = mn;
        l_i *= alpha;
#pragma unroll
        for (int dt = 0; dt < 8; ++dt)
#pragma unroll
          for (int r = 0; r < 4; ++r) acc[dt][r] *= alpha;
      }

      float rs = 0.0f;
#pragma unroll
      for (int kkt = 0; kkt < 2; ++kkt)
#pragma unroll
        for (int r = 0; r < 4; ++r) {
          const float p = __expf(st[kkt][r] - m_i);
          st[kkt][r] = p;
          rs += p;
        }
      rs += __shfl_xor(rs, 16);
      rs += __shfl_xor(rs, 32);
      l_i += rs;

#pragma unroll
      for (int kkt = 0; kkt < 2; ++kkt) {
        ushort4 pk;
        pk.x = f2bf(st[kkt][0]);
        pk.y = f2bf(st[kkt][1]);
        pk.z = f2bf(st[kkt][2]);
        pk.w = f2bf(st[kkt][3]);
        *(ushort4*)(&Ssh[w * 16 + lane16][kkt * 16 + quad * 4]) = pk;
      }
    }

    // --- O^T += V^T x P^T : 128 d x 16 q, contraction 32 kk ---
    const short8 pa =
        *(const short8*)(&Ssh[w * 16 + lane16][quad * 8]);
    const int vpos = (quad ^ (lane16 & 3)) * 8;
    __builtin_amdgcn_s_setprio(1);
#pragma unroll
    for (int dt = 0; dt < 8; ++dt) {
      const short8 vf = *(const short8*)(Vc + (dt * 16 + lane16) * 32 + vpos);
      acc[dt] = __builtin_amdgcn_mfma_f32_16x16x32_bf16(
          vf, pa, acc[dt], 0, 0, 0);
    }
    __builtin_amdgcn_s_setprio(0);
  }

  // epilogue: O^T row=d=dt*16+quad*4+r, col=q = q0 + w*16 + lane16
  {
    const float inv = 1.0f / l_i;
    const int q = q0 + w * 16 + lane16;
    unsigned short* op = ctx + ((size_t)b * SS + q) * EE + h * DD + quad * 4;
#pragma unroll
    for (int dt = 0; dt < 8; ++dt) {
      ushort4 o;
      o.x = f2bf(acc[dt][0] * inv);
      o.y = f2bf(acc[dt][1] * inv);
      o.z = f2bf(acc[dt][2] * inv);
      o.w = f2bf(acc[dt][3] * inv);
      *(ushort4*)(op + dt * 16) = o;
    }
  }
}

// ---------------------------------------------------------------------------
// Launch
// ---------------------------------------------------------------------------
extern "C" void kernel_launch(void* const* d_in, const int* in_sizes, int n_in,
                              void* d_out, int out_size, void* d_ws,
                              size_t ws_size, hipStream_t stream) {
  const float* x    = (const float*)d_in[0];
  const float* wqkv = (const float*)d_in[1];
  const float* bqkv = (const float*)d_in[2];
  const float* wout = (const float*)d_in[3];
  const float* bout = (const float*)d_in[4];
  float* out = (float*)d_out;

  unsigned short* qkvb = (unsigned short*)d_ws;      // 25165824 elems
  unsigned short* xb   = qkvb + (size_t)25165824;    //  8388608
  unsigned short* wqb  = xb + (size_t)8388608;       // 12582912
  unsigned short* ctxb = wqb + (size_t)12582912;     //  8388608
  unsigned short* wob  = ctxb + (size_t)8388608;     //  4194304
  unsigned short* vtb  = wob + (size_t)4194304;      //  8388608

  const int M = BB * SS;  // 4096

  cast_f32_bf16<<<8192, 256, 0, stream>>>(x, xb, 2097152);
  cast_f32_bf16<<<12288, 256, 0, stream>>>(wqkv, wqb, 3145728);
  cast_f32_bf16<<<4096, 256, 0, stream>>>(wout, wob, 1048576);

  {
    // 256x192 balanced grid: 16 x 32 = 512 blocks = exactly 2 rounds
    gemm_bf16_256x192<unsigned short><<<dim3(512), 512, 0, stream>>>(
        xb, wqb, bqkv, qkvb, M, FF, EE);
  }
  {
    const int total = BB * SS * HH * 64;
    rotary_kernel<<<total / 256, 256, 0, stream>>>(qkvb);
  }
  {
    dim3 grid(SS / 64, DD / 64, BB * HH);
    transpose_v<<<grid, 256, 0, stream>>>(qkvb, vtb);
  }
  {
    // one q-tile per block, 8 waves: 512 blocks = 2 blocks/CU
    attn_mfma<<<dim3(512), 512, 0, stream>>>(qkvb, vtb, ctxb);
  }
  {
    // out-projection: 256x128 balanced grid, 16 x 16 = 256 blocks = 1 round
    gemm_bf16_256x128<float><<<dim3(256), 512, 0, stream>>>(
        ctxb, wob, bout, out, M, EE, EE);
  }
}

// Round 9
// 391.552 us; speedup vs baseline: 1.0724x; 1.0171x over previous
//
#include <hip/hip_runtime.h>
#include <math.h>

// Problem constants
#define BB 2
#define SS 2048
#define EE 2048
#define HH 16
#define DD 128
#define FF 6144   // 3*E

typedef __attribute__((ext_vector_type(8))) short short8;
typedef __attribute__((ext_vector_type(4))) float floatx4;

static __device__ __forceinline__ unsigned short f2bf(float x) {
  unsigned u = __float_as_uint(x);
  u += 0x7fffu + ((u >> 16) & 1u);
  return (unsigned short)(u >> 16);
}
static __device__ __forceinline__ float bf2f(unsigned short h) {
  return __uint_as_float((unsigned)h << 16);
}

#define GLOAD_LDS16(gp, lp)                                       \
  __builtin_amdgcn_global_load_lds(                               \
      (const __attribute__((address_space(1))) void*)(gp),        \
      (__attribute__((address_space(3))) void*)(lp), 16, 0, 0)

// ---------------------------------------------------------------------------
// merged fp32 -> bf16 cast for x, wqkv, wout (one launch instead of three)
// ---------------------------------------------------------------------------
__global__ __launch_bounds__(256) void cast_all(
    const float* __restrict__ x, const float* __restrict__ wqkv,
    const float* __restrict__ wout, unsigned short* __restrict__ xb,
    unsigned short* __restrict__ wqb, unsigned short* __restrict__ wob) {
  const int i = blockIdx.x * 256 + threadIdx.x;
  const float* src;
  unsigned short* dst;
  int off;
  if (i < 2097152) {
    src = x; dst = xb; off = i;
  } else if (i < 5242880) {
    src = wqkv; dst = wqb; off = i - 2097152;
  } else {
    src = wout; dst = wob; off = i - 5242880;
  }
  const float4 v = ((const float4*)src)[off];
  ushort4 o;
  o.x = f2bf(v.x); o.y = f2bf(v.y); o.z = f2bf(v.z); o.w = f2bf(v.w);
  ((ushort4*)dst)[off] = o;
}

static __device__ __forceinline__ void store_out(float* p, float v) { *p = v; }
static __device__ __forceinline__ void store_out(unsigned short* p, float v) {
  *p = f2bf(v);
}

// ---------------------------------------------------------------------------
// 256x192 bf16 GEMM (BK=64), grid-balanced (unchanged: 110 us, MfmaUtil 40%).
// ---------------------------------------------------------------------------
template <typename OutT>
__global__ __launch_bounds__(512, 2) void gemm_bf16_256x192(
    const unsigned short* __restrict__ A, const unsigned short* __restrict__ Bt,
    const float* __restrict__ bias, OutT* __restrict__ C,
    int M, int N, int K) {
  __shared__ __align__(16) unsigned short As[2][16384];  // 256x64
  __shared__ __align__(16) unsigned short Bs[2][12288];  // 192x64

  const int tid = threadIdx.x;
  const int w = tid >> 6;
  const int L = tid & 63;
  const int lane16 = L & 15;
  const int quad = L >> 4;
  const int wm = w >> 2;   // 0..1
  const int wn = w & 3;    // 0..3

  const int nby = M >> 8;          // 16
  const int q8 = gridDim.x >> 3;   // 64
  const int wg = (blockIdx.x & 7) * q8 + (blockIdx.x >> 3);
  const int by = wg % nby;
  const int bx = wg / nby;
  const int m0 = by << 8;
  const int n0 = bx * 192;

  const int lA = ((w >> 1) << 4) + (L >> 2);
  const int scol = ((w & 1) << 5) + (((L & 3) * 8) ^ ((L & 32) ? 16 : 0));
  unsigned aoff[4], boff[3];
#pragma unroll
  for (int j = 0; j < 4; ++j)
    aoff[j] = (unsigned)(m0 + j * 64 + lA) * (unsigned)K + scol;
#pragma unroll
  for (int j = 0; j < 3; ++j)
    boff[j] = (unsigned)(n0 + j * 64 + lA) * (unsigned)K + scol;
  const int ldst = w * 512;

  const int sq = (quad * 8) ^ ((lane16 & 8) << 1);
  const int rbase = lane16 * 32 + sq;

  floatx4 acc[8][3] = {};

  GLOAD_LDS16(A + aoff[0], &As[0][0 * 4096 + ldst]);
  GLOAD_LDS16(A + aoff[1], &As[0][1 * 4096 + ldst]);
  GLOAD_LDS16(A + aoff[2], &As[0][2 * 4096 + ldst]);
  GLOAD_LDS16(A + aoff[3], &As[0][3 * 4096 + ldst]);
  GLOAD_LDS16(Bt + boff[0], &Bs[0][0 * 4096 + ldst]);
  GLOAD_LDS16(Bt + boff[1], &Bs[0][1 * 4096 + ldst]);
  GLOAD_LDS16(Bt + boff[2], &Bs[0][2 * 4096 + ldst]);
  GLOAD_LDS16(Bt + boff[0] + 64, &Bs[1][0 * 4096 + ldst]);
  GLOAD_LDS16(Bt + boff[1] + 64, &Bs[1][1 * 4096 + ldst]);
  GLOAD_LDS16(Bt + boff[2] + 64, &Bs[1][2 * 4096 + ldst]);
  asm volatile("s_waitcnt vmcnt(3)" ::: "memory");
  __builtin_amdgcn_sched_barrier(0);
  __builtin_amdgcn_s_barrier();

  const int NT = K >> 6;  // 32
  short8 a[4][2], b[3][2];

  for (int t = 0; t < NT; ++t) {
    const int c = t & 1;
    const unsigned kn1 = (unsigned)(t + 1) << 6;
    const unsigned kn2 = (unsigned)(t + 2) << 6;
    const unsigned short* Ac = &As[c][0];
    const unsigned short* Bc = &Bs[c][0];

    // P0: read a-lo(8) + b(6); stage A(t+1); 24 MFMA
#pragma unroll
    for (int mi = 0; mi < 4; ++mi)
#pragma unroll
      for (int kk = 0; kk < 2; ++kk)
        a[mi][kk] = *(const short8*)(Ac + (wm * 2) * 4096 +
                                     ((mi * 2 + kk) * 512) + rbase);
#pragma unroll
    for (int ni = 0; ni < 3; ++ni) {
      const int f = wn * 3 + ni;
#pragma unroll
      for (int kk = 0; kk < 2; ++kk)
        b[ni][kk] = *(const short8*)(Bc + (f >> 2) * 4096 +
                                     (((f & 3) * 2 + kk) * 512) + rbase);
    }
    GLOAD_LDS16(A + aoff[0] + kn1, &As[c ^ 1][0 * 4096 + ldst]);
    GLOAD_LDS16(A + aoff[1] + kn1, &As[c ^ 1][1 * 4096 + ldst]);
    GLOAD_LDS16(A + aoff[2] + kn1, &As[c ^ 1][2 * 4096 + ldst]);
    GLOAD_LDS16(A + aoff[3] + kn1, &As[c ^ 1][3 * 4096 + ldst]);
    __builtin_amdgcn_s_setprio(1);
#pragma unroll
    for (int mi = 0; mi < 4; ++mi)
#pragma unroll
      for (int ni = 0; ni < 3; ++ni)
#pragma unroll
        for (int kk = 0; kk < 2; ++kk)
          acc[mi][ni] = __builtin_amdgcn_mfma_f32_16x16x32_bf16(
              a[mi][kk], b[ni][kk], acc[mi][ni], 0, 0, 0);
    __builtin_amdgcn_s_setprio(0);
    __builtin_amdgcn_sched_barrier(0);
    __builtin_amdgcn_s_barrier();

    // P1: read a-hi(8); stage B(t+2); 24 MFMA; vmcnt(3)
#pragma unroll
    for (int mi = 0; mi < 4; ++mi)
#pragma unroll
      for (int kk = 0; kk < 2; ++kk)
        a[mi][kk] = *(const short8*)(Ac + (wm * 2 + 1) * 4096 +
                                     ((mi * 2 + kk) * 512) + rbase);
    GLOAD_LDS16(Bt + boff[0] + kn2, &Bs[c][0 * 4096 + ldst]);
    GLOAD_LDS16(Bt + boff[1] + kn2, &Bs[c][1 * 4096 + ldst]);
    GLOAD_LDS16(Bt + boff[2] + kn2, &Bs[c][2 * 4096 + ldst]);
    __builtin_amdgcn_s_setprio(1);
#pragma unroll
    for (int mi = 0; mi < 4; ++mi)
#pragma unroll
      for (int ni = 0; ni < 3; ++ni)
#pragma unroll
        for (int kk = 0; kk < 2; ++kk)
          acc[4 + mi][ni] = __builtin_amdgcn_mfma_f32_16x16x32_bf16(
              a[mi][kk], b[ni][kk], acc[4 + mi][ni], 0, 0, 0);
    __builtin_amdgcn_s_setprio(0);
    asm volatile("s_waitcnt vmcnt(3)" ::: "memory");
    __builtin_amdgcn_sched_barrier(0);
    __builtin_amdgcn_s_barrier();
  }

  // epilogue
#pragma unroll
  for (int ni = 0; ni < 3; ++ni) {
    const int col = n0 + wn * 48 + ni * 16 + lane16;
    const float bv = bias[col];
#pragma unroll
    for (int mi = 0; mi < 8; ++mi) {
      const int row = m0 + wm * 128 + mi * 16 + quad * 4;
#pragma unroll
      for (int r = 0; r < 4; ++r)
        store_out(&C[(size_t)(row + r) * N + col], acc[mi][ni][r] + bv);
    }
  }
}

// ---------------------------------------------------------------------------
// 256x128 bf16 GEMM (BK=64): out-projection, grid 256 = 1 round (unchanged).
// ---------------------------------------------------------------------------
template <typename OutT>
__global__ __launch_bounds__(512, 2) void gemm_bf16_256x128(
    const unsigned short* __restrict__ A, const unsigned short* __restrict__ Bt,
    const float* __restrict__ bias, OutT* __restrict__ C,
    int M, int N, int K) {
  __shared__ __align__(16) unsigned short As[2][16384];  // 256x64
  __shared__ __align__(16) unsigned short Bs[2][8192];   // 128x64

  const int tid = threadIdx.x;
  const int w = tid >> 6;
  const int L = tid & 63;
  const int lane16 = L & 15;
  const int quad = L >> 4;
  const int wm = w >> 2;   // 0..1
  const int wn = w & 3;    // 0..3

  const int nby = M >> 8;          // 16
  const int q8 = gridDim.x >> 3;   // 32
  const int wg = (blockIdx.x & 7) * q8 + (blockIdx.x >> 3);
  const int by = wg % nby;
  const int bx = wg / nby;
  const int m0 = by << 8;
  const int n0 = bx << 7;

  const int lA = ((w >> 1) << 4) + (L >> 2);
  const int scol = ((w & 1) << 5) + (((L & 3) * 8) ^ ((L & 32) ? 16 : 0));
  unsigned aoff[4], boff[2];
#pragma unroll
  for (int j = 0; j < 4; ++j)
    aoff[j] = (unsigned)(m0 + j * 64 + lA) * (unsigned)K + scol;
#pragma unroll
  for (int j = 0; j < 2; ++j)
    boff[j] = (unsigned)(n0 + j * 64 + lA) * (unsigned)K + scol;
  const int ldst = w * 512;

  const int sq = (quad * 8) ^ ((lane16 & 8) << 1);
  const int rbase = lane16 * 32 + sq;

  floatx4 acc[8][2] = {};

  GLOAD_LDS16(A + aoff[0], &As[0][0 * 4096 + ldst]);
  GLOAD_LDS16(A + aoff[1], &As[0][1 * 4096 + ldst]);
  GLOAD_LDS16(A + aoff[2], &As[0][2 * 4096 + ldst]);
  GLOAD_LDS16(A + aoff[3], &As[0][3 * 4096 + ldst]);
  GLOAD_LDS16(Bt + boff[0], &Bs[0][0 * 4096 + ldst]);
  GLOAD_LDS16(Bt + boff[1], &Bs[0][1 * 4096 + ldst]);
  GLOAD_LDS16(Bt + boff[0] + 64, &Bs[1][0 * 4096 + ldst]);
  GLOAD_LDS16(Bt + boff[1] + 64, &Bs[1][1 * 4096 + ldst]);
  asm volatile("s_waitcnt vmcnt(2)" ::: "memory");
  __builtin_amdgcn_sched_barrier(0);
  __builtin_amdgcn_s_barrier();

  const int NT = K >> 6;  // 32
  short8 a[4][2], b[2][2];

  for (int t = 0; t < NT; ++t) {
    const int c = t & 1;
    const unsigned kn1 = (unsigned)(t + 1) << 6;
    const unsigned kn2 = (unsigned)(t + 2) << 6;
    const unsigned short* Ac = &As[c][0];
    const unsigned short* Bc = &Bs[c][0];

    // P0: read a-lo(8) + b(4); stage A(t+1); 16 MFMA
#pragma unroll
    for (int mi = 0; mi < 4; ++mi)
#pragma unroll
      for (int kk = 0; kk < 2; ++kk)
        a[mi][kk] = *(const short8*)(Ac + (wm * 2) * 4096 +
                                     ((mi * 2 + kk) * 512) + rbase);
#pragma unroll
    for (int ni = 0; ni < 2; ++ni) {
      const int f = wn * 2 + ni;
#pragma unroll
      for (int kk = 0; kk < 2; ++kk)
        b[ni][kk] = *(const short8*)(Bc + (f >> 2) * 4096 +
                                     (((f & 3) * 2 + kk) * 512) + rbase);
    }
    GLOAD_LDS16(A + aoff[0] + kn1, &As[c ^ 1][0 * 4096 + ldst]);
    GLOAD_LDS16(A + aoff[1] + kn1, &As[c ^ 1][1 * 4096 + ldst]);
    GLOAD_LDS16(A + aoff[2] + kn1, &As[c ^ 1][2 * 4096 + ldst]);
    GLOAD_LDS16(A + aoff[3] + kn1, &As[c ^ 1][3 * 4096 + ldst]);
    __builtin_amdgcn_s_setprio(1);
#pragma unroll
    for (int mi = 0; mi < 4; ++mi)
#pragma unroll
      for (int ni = 0; ni < 2; ++ni)
#pragma unroll
        for (int kk = 0; kk < 2; ++kk)
          acc[mi][ni] = __builtin_amdgcn_mfma_f32_16x16x32_bf16(
              a[mi][kk], b[ni][kk], acc[mi][ni], 0, 0, 0);
    __builtin_amdgcn_s_setprio(0);
    __builtin_amdgcn_sched_barrier(0);
    __builtin_amdgcn_s_barrier();

    // P1: read a-hi(8); stage B(t+2); 16 MFMA; vmcnt(2)
#pragma unroll
    for (int mi = 0; mi < 4; ++mi)
#pragma unroll
      for (int kk = 0; kk < 2; ++kk)
        a[mi][kk] = *(const short8*)(Ac + (wm * 2 + 1) * 4096 +
                                     ((mi * 2 + kk) * 512) + rbase);
    GLOAD_LDS16(Bt + boff[0] + kn2, &Bs[c][0 * 4096 + ldst]);
    GLOAD_LDS16(Bt + boff[1] + kn2, &Bs[c][1 * 4096 + ldst]);
    __builtin_amdgcn_s_setprio(1);
#pragma unroll
    for (int mi = 0; mi < 4; ++mi)
#pragma unroll
      for (int ni = 0; ni < 2; ++ni)
#pragma unroll
        for (int kk = 0; kk < 2; ++kk)
          acc[4 + mi][ni] = __builtin_amdgcn_mfma_f32_16x16x32_bf16(
              a[mi][kk], b[ni][kk], acc[4 + mi][ni], 0, 0, 0);
    __builtin_amdgcn_s_setprio(0);
    asm volatile("s_waitcnt vmcnt(2)" ::: "memory");
    __builtin_amdgcn_sched_barrier(0);
    __builtin_amdgcn_s_barrier();
  }

  // epilogue
#pragma unroll
  for (int ni = 0; ni < 2; ++ni) {
    const int col = n0 + wn * 32 + ni * 16 + lane16;
    const float bv = bias[col];
#pragma unroll
    for (int mi = 0; mi < 8; ++mi) {
      const int row = m0 + wm * 128 + mi * 16 + quad * 4;
#pragma unroll
      for (int r = 0; r < 4; ++r)
        store_out(&C[(size_t)(row + r) * N + col], acc[mi][ni][r] + bv);
    }
  }
}

// ---------------------------------------------------------------------------
// Merged rotary (blocks 0..16383) + V transpose (blocks 16384..18431).
// rotary needs BB*SS*HH*64/256 = 16384 blocks.
// ---------------------------------------------------------------------------
__global__ __launch_bounds__(256) void rope_transpose(
    unsigned short* __restrict__ qkv, unsigned short* __restrict__ vt) {
  if (blockIdx.x < 16384) {
    // rotary on q,k
    const int idx = blockIdx.x * 256 + threadIdx.x;
    const int d = idx & 63;
    const int h = (idx >> 6) & (HH - 1);
    const int s = (idx >> 10) & (SS - 1);
    const int b = idx >> 21;

    const float inv_freq = __expf(-(float)d * 0.14391156509f);
    float sn, c;
    __sincosf((float)s * inv_freq, &sn, &c);

    const size_t base = ((size_t)b * SS + s) * FF + h * DD + d;
    unsigned short* q = qkv + base;
    unsigned short* k = qkv + base + EE;

    const float q1 = bf2f(q[0]), q2 = bf2f(q[64]);
    q[0]  = f2bf(q1 * c - q2 * sn);
    q[64] = f2bf(q2 * c + q1 * sn);
    const float k1 = bf2f(k[0]), k2 = bf2f(k[64]);
    k[0]  = f2bf(k1 * c - k2 * sn);
    k[64] = f2bf(k2 * c + k1 * sn);
  } else {
    // V transpose: [b][s][h][d] -> vt[b*H+h][d][s]
    __shared__ unsigned short T[64][72];
    const int idx = blockIdx.x - 16384;
    const int t = threadIdx.x;
    const int s0 = (idx & 31) * 64;
    const int d0 = ((idx >> 5) & 1) * 64;
    const int bh = idx >> 6;
    const int b = bh >> 4, h = bh & 15;
    {
      const int r = t >> 2, c = (t & 3) * 16;
      const unsigned short* src =
          qkv + ((size_t)b * SS + s0 + r) * FF + 2 * EE + h * DD + d0 + c;
      const uint4 u0 = *(const uint4*)src;
      const uint4 u1 = *(const uint4*)(src + 8);
      *(uint4*)&T[r][c] = u0;
      *(uint4*)&T[r][c + 8] = u1;
    }
    __syncthreads();
    {
      const int rr = t >> 2, cc = (t & 3) * 16;
      unsigned short vals[16];
#pragma unroll
      for (int j = 0; j < 16; ++j) vals[j] = T[cc + j][rr];
      unsigned short* dst =
          vt + (size_t)bh * DD * SS + (size_t)(d0 + rr) * SS + s0 + cc;
      *(uint4*)dst = *(uint4*)&vals[0];
      *(uint4*)(dst + 8) = *(uint4*)&vals[8];
    }
  }
}

// ---------------------------------------------------------------------------
// MFMA flash attention, causal: 4 waves x 32 q-rows, KVBLK=64 (half the
// barriers vs KVBLK=32; 2-mi frag reuse halves K/V LDS reads per MFMA).
// LDS = K 2x16K + V 2x16K + Ssh 128x64 = 80 KiB -> 2 blocks/CU.
// Ssh: XOR slot-swizzle (slot ^ 2*(q&7), bit0 kept). V: octet ^ (d&7).
// Grid 512 = LPT heavy-first + XCD co-location (bh = flat&31) + defer-max.
// ---------------------------------------------------------------------------
#define ATQ 128
#define ATK 64
#define NQT (SS / ATQ)  // 16

__global__ __launch_bounds__(256, 2) void attn_mfma(
    const unsigned short* __restrict__ qkv,
    const unsigned short* __restrict__ vt,
    unsigned short* __restrict__ ctx) {
  __shared__ __align__(16) unsigned short Ksh[2][ATK * DD];  // [kk][d] 16KB
  __shared__ __align__(16) unsigned short Vsh[2][DD * ATK];  // [d][kk] 16KB
  __shared__ __align__(16) unsigned short Ssh[ATQ][64];      // P, swizzled

  const int tid = threadIdx.x;
  const int L = tid & 63;
  const int w = tid >> 6;          // 0..3
  const int lane16 = L & 15;
  const int quad = L >> 4;

  const int flat = blockIdx.x;        // 0..511
  const int bh_lin = flat & 31;       // fastest -> flat%8 const per bh
  const int qb = (NQT - 1) - (flat >> 5);  // heavy q-tiles first (LPT)
  const int b = bh_lin >> 4;
  const int h = bh_lin & 15;
  const int bh = b * HH + h;
  const float scale = 0.08838834764831845f;

  // staging: 4 rounds K + 4 rounds V, 256 thr x 16B = 4KB per round
  size_t koff[4], voff[4];
#pragma unroll
  for (int j = 0; j < 4; ++j) {
    const int ik = j * 256 + tid;
    const int kk = ik >> 4;
    const int ock = (ik & 15) ^ (kk & 15);
    koff[j] = ((size_t)b * SS + kk) * FF + EE + h * DD + ock * 8;
    const int d = ik >> 3;
    const int ocv = (ik & 7) ^ (d & 7);
    voff[j] = (size_t)bh * DD * SS + (size_t)d * SS + ocv * 8;
  }
  const int dstb = w * 512;  // per-wave ushort offset within a 4KB round

  const int q0 = qb * ATQ;

  // Q frags (B-operand): wave w owns rows q0 + w*32 + mi*16 + lane16
  short8 qf[2][4];
#pragma unroll
  for (int mi = 0; mi < 2; ++mi) {
    const int q = q0 + w * 32 + mi * 16 + lane16;
    const unsigned short* qp =
        qkv + ((size_t)b * SS + q) * FF + h * DD + quad * 8;
#pragma unroll
    for (int dc = 0; dc < 4; ++dc)
      qf[mi][dc] = *(const short8*)(qp + dc * 32);
  }

  floatx4 acc[8][2] = {};
  float m_i[2] = {-3.0e38f, -3.0e38f};
  float l_i[2] = {0.0f, 0.0f};

  const int nkt = 2 * qb + 2;
  const int mykt = 2 * qb + (w >> 1);

  // prologue: stage tile 0 -> buf 0
#pragma unroll
  for (int j = 0; j < 4; ++j) {
    GLOAD_LDS16(qkv + koff[j], &Ksh[0][j * 2048 + dstb]);
    GLOAD_LDS16(vt + voff[j], &Vsh[0][j * 2048 + dstb]);
  }

  for (int kt = 0; kt < nkt; ++kt) {
    const int cur = kt & 1;
    __syncthreads();  // drains stage(kt)
    if (kt + 1 < nkt) {
      const size_t ka = (size_t)(kt + 1) * ATK * FF;
      const int va = (kt + 1) * ATK;
#pragma unroll
      for (int j = 0; j < 4; ++j) {
        GLOAD_LDS16(qkv + koff[j] + ka, &Ksh[cur ^ 1][j * 2048 + dstb]);
        GLOAD_LDS16(vt + voff[j] + va, &Vsh[cur ^ 1][j * 2048 + dstb]);
      }
    }
    if (kt > mykt) continue;  // fully-masked tile for this wave
    const int k0 = kt * ATK;
    const unsigned short* Kc = Ksh[cur];
    const unsigned short* Vc = Vsh[cur];

    // --- S^T = K x Q^T : 64 kk x 32 q per wave (32 MFMA) ---
    floatx4 st[4][2] = {};
    __builtin_amdgcn_s_setprio(1);
#pragma unroll
    for (int kkt = 0; kkt < 4; ++kkt) {
      const unsigned short* krow = Kc + (kkt * 16 + lane16) * 128;
#pragma unroll
      for (int dc = 0; dc < 4; ++dc) {
        const short8 kf =
            *(const short8*)(krow + ((dc * 4 + quad) ^ lane16) * 8);
#pragma unroll
        for (int mi = 0; mi < 2; ++mi)
          st[kkt][mi] = __builtin_amdgcn_mfma_f32_16x16x32_bf16(
              kf, qf[mi][dc], st[kkt][mi], 0, 0, 0);
      }
    }
    __builtin_amdgcn_s_setprio(0);

    // --- scale + causal mask (diagonal tile only) ---
    const bool needmask = (kt == mykt);
#pragma unroll
    for (int mi = 0; mi < 2; ++mi) {
      const int q_glob = q0 + w * 32 + mi * 16 + lane16;
#pragma unroll
      for (int kkt = 0; kkt < 4; ++kkt) {
        const int kkb = k0 + kkt * 16 + quad * 4;
#pragma unroll
        for (int r = 0; r < 4; ++r) {
          float v = st[kkt][mi][r] * scale;
          if (needmask && (kkb + r) > q_glob) v = -3.0e38f;
          st[kkt][mi][r] = v;
        }
      }
    }

    // --- online softmax (T13 defer-max), 16 vals per mi ---
#pragma unroll
    for (int mi = 0; mi < 2; ++mi) {
      float tm = -3.0e38f;
#pragma unroll
      for (int kkt = 0; kkt < 4; ++kkt)
#pragma unroll
        for (int r = 0; r < 4; ++r) tm = fmaxf(tm, st[kkt][mi][r]);
      tm = fmaxf(tm, __shfl_xor(tm, 16));
      tm = fmaxf(tm, __shfl_xor(tm, 32));

      const bool need = !__all(tm - m_i[mi] <= 8.0f);
      if (need) {
        const float mn = fmaxf(m_i[mi], tm);
        const float alpha = __expf(m_i[mi] - mn);
        m_i[mi] = mn;
        l_i[mi] *= alpha;
#pragma unroll
        for (int dt = 0; dt < 8; ++dt)
#pragma unroll
          for (int r = 0; r < 4; ++r) acc[dt][mi][r] *= alpha;
      }

      float rs = 0.0f;
#pragma unroll
      for (int kkt = 0; kkt < 4; ++kkt)
#pragma unroll
        for (int r = 0; r < 4; ++r) {
          const float p = __expf(st[kkt][mi][r] - m_i[mi]);
          st[kkt][mi][r] = p;
          rs += p;
        }
      rs += __shfl_xor(rs, 16);
      rs += __shfl_xor(rs, 32);
      l_i[mi] += rs;

      // P write: row q, slot (kkt*4+quad) ^ 2*(q&7)  (bit0 untouched)
      const int row = w * 32 + mi * 16 + lane16;
      const int sw = 2 * (lane16 & 7);
#pragma unroll
      for (int kkt = 0; kkt < 4; ++kkt) {
        ushort4 pk;
        pk.x = f2bf(st[kkt][mi][0]);
        pk.y = f2bf(st[kkt][mi][1]);
        pk.z = f2bf(st[kkt][mi][2]);
        pk.w = f2bf(st[kkt][mi][3]);
        *(ushort4*)(&Ssh[row][((kkt * 4 + quad) ^ sw) * 4]) = pk;
      }
    }

    // --- O^T += V^T x P^T : 128 d x 32 q, contraction 64 kk (32 MFMA) ---
    short8 pa[2][2];
#pragma unroll
    for (int mi = 0; mi < 2; ++mi) {
      const int row = w * 32 + mi * 16 + lane16;
      const int sw = 2 * (lane16 & 7);
#pragma unroll
      for (int ks = 0; ks < 2; ++ks)
        pa[mi][ks] =
            *(const short8*)(&Ssh[row][((ks * 8 + quad * 2) ^ sw) * 4]);
    }
    __builtin_amdgcn_s_setprio(1);
#pragma unroll
    for (int dt = 0; dt < 8; ++dt) {
      const unsigned short* vrow = Vc + (dt * 16 + lane16) * 64;
#pragma unroll
      for (int ks = 0; ks < 2; ++ks) {
        const short8 vf =
            *(const short8*)(vrow + (((ks * 4 + quad) ^ (lane16 & 7)) * 8));
#pragma unroll
        for (int mi = 0; mi < 2; ++mi)
          acc[dt][mi] = __builtin_amdgcn_mfma_f32_16x16x32_bf16(
              vf, pa[mi][ks], acc[dt][mi], 0, 0, 0);
      }
    }
    __builtin_amdgcn_s_setprio(0);
  }

  // epilogue: O^T row=d=dt*16+quad*4+r, col=q = q0 + w*32 + mi*16 + lane16
#pragma unroll
  for (int mi = 0; mi < 2; ++mi) {
    const float inv = 1.0f / l_i[mi];
    const int q = q0 + w * 32 + mi * 16 + lane16;
    unsigned short* op = ctx + ((size_t)b * SS + q) * EE + h * DD + quad * 4;
#pragma unroll
    for (int dt = 0; dt < 8; ++dt) {
      ushort4 o;
      o.x = f2bf(acc[dt][mi][0] * inv);
      o.y = f2bf(acc[dt][mi][1] * inv);
      o.z = f2bf(acc[dt][mi][2] * inv);
      o.w = f2bf(acc[dt][mi][3] * inv);
      *(ushort4*)(op + dt * 16) = o;
    }
  }
}

// ---------------------------------------------------------------------------
// Launch
// ---------------------------------------------------------------------------
extern "C" void kernel_launch(void* const* d_in, const int* in_sizes, int n_in,
                              void* d_out, int out_size, void* d_ws,
                              size_t ws_size, hipStream_t stream) {
  const float* x    = (const float*)d_in[0];
  const float* wqkv = (const float*)d_in[1];
  const float* bqkv = (const float*)d_in[2];
  const float* wout = (const float*)d_in[3];
  const float* bout = (const float*)d_in[4];
  float* out = (float*)d_out;

  unsigned short* qkvb = (unsigned short*)d_ws;      // 25165824 elems
  unsigned short* xb   = qkvb + (size_t)25165824;    //  8388608
  unsigned short* wqb  = xb + (size_t)8388608;       // 12582912
  unsigned short* ctxb = wqb + (size_t)12582912;     //  8388608
  unsigned short* wob  = ctxb + (size_t)8388608;     //  4194304
  unsigned short* vtb  = wob + (size_t)4194304;      //  8388608

  const int M = BB * SS;  // 4096

  // all three casts in one launch: (2097152 + 3145728 + 1048576)/256 = 24576
  cast_all<<<24576, 256, 0, stream>>>(x, wqkv, wout, xb, wqb, wob);

  {
    // 256x192 balanced grid: 16 x 32 = 512 blocks = exactly 2 rounds
    gemm_bf16_256x192<unsigned short><<<dim3(512), 512, 0, stream>>>(
        xb, wqb, bqkv, qkvb, M, FF, EE);
  }
  {
    // rotary (16384 blocks) + V transpose (2048 blocks) in one launch
    rope_transpose<<<18432, 256, 0, stream>>>(qkvb, vtb);
  }
  {
    // 4 waves x 32 rows, KVBLK=64: 512 blocks, 2 blocks/CU
    attn_mfma<<<dim3(512), 256, 0, stream>>>(qkvb, vtb, ctxb);
  }
  {
    // out-projection: 256x128 balanced grid, 16 x 16 = 256 blocks = 1 round
    gemm_bf16_256x128<float><<<dim3(256), 512, 0, stream>>>(
        ctxb, wob, bout, out, M, EE, EE);
  }
}

// Round 10
// 384.805 us; speedup vs baseline: 1.0912x; 1.0175x over previous
//
#include <hip/hip_runtime.h>
#include <math.h>

// Problem constants
#define BB 2
#define SS 2048
#define EE 2048
#define HH 16
#define DD 128
#define FF 6144   // 3*E

typedef __attribute__((ext_vector_type(8))) short short8;
typedef __attribute__((ext_vector_type(4))) float floatx4;

static __device__ __forceinline__ unsigned short f2bf(float x) {
  unsigned u = __float_as_uint(x);
  u += 0x7fffu + ((u >> 16) & 1u);
  return (unsigned short)(u >> 16);
}
static __device__ __forceinline__ float bf2f(unsigned short h) {
  return __uint_as_float((unsigned)h << 16);
}

#define GLOAD_LDS16(gp, lp)                                       \
  __builtin_amdgcn_global_load_lds(                               \
      (const __attribute__((address_space(1))) void*)(gp),        \
      (__attribute__((address_space(3))) void*)(lp), 16, 0, 0)

// ---------------------------------------------------------------------------
// merged fp32 -> bf16 cast for x, wqkv, wout (one launch instead of three)
// ---------------------------------------------------------------------------
__global__ __launch_bounds__(256) void cast_all(
    const float* __restrict__ x, const float* __restrict__ wqkv,
    const float* __restrict__ wout, unsigned short* __restrict__ xb,
    unsigned short* __restrict__ wqb, unsigned short* __restrict__ wob) {
  const int i = blockIdx.x * 256 + threadIdx.x;
  const float* src;
  unsigned short* dst;
  int off;
  if (i < 2097152) {
    src = x; dst = xb; off = i;
  } else if (i < 5242880) {
    src = wqkv; dst = wqb; off = i - 2097152;
  } else {
    src = wout; dst = wob; off = i - 5242880;
  }
  const float4 v = ((const float4*)src)[off];
  ushort4 o;
  o.x = f2bf(v.x); o.y = f2bf(v.y); o.z = f2bf(v.z); o.w = f2bf(v.w);
  ((ushort4*)dst)[off] = o;
}

static __device__ __forceinline__ void store_out(float* p, float v) { *p = v; }
static __device__ __forceinline__ void store_out(unsigned short* p, float v) {
  *p = f2bf(v);
}

// ---------------------------------------------------------------------------
// 256x192 bf16 GEMM (BK=64), grid-balanced (unchanged: 111 us, MfmaUtil 40%).
// ---------------------------------------------------------------------------
template <typename OutT>
__global__ __launch_bounds__(512, 2) void gemm_bf16_256x192(
    const unsigned short* __restrict__ A, const unsigned short* __restrict__ Bt,
    const float* __restrict__ bias, OutT* __restrict__ C,
    int M, int N, int K) {
  __shared__ __align__(16) unsigned short As[2][16384];  // 256x64
  __shared__ __align__(16) unsigned short Bs[2][12288];  // 192x64

  const int tid = threadIdx.x;
  const int w = tid >> 6;
  const int L = tid & 63;
  const int lane16 = L & 15;
  const int quad = L >> 4;
  const int wm = w >> 2;   // 0..1
  const int wn = w & 3;    // 0..3

  const int nby = M >> 8;          // 16
  const int q8 = gridDim.x >> 3;   // 64
  const int wg = (blockIdx.x & 7) * q8 + (blockIdx.x >> 3);
  const int by = wg % nby;
  const int bx = wg / nby;
  const int m0 = by << 8;
  const int n0 = bx * 192;

  const int lA = ((w >> 1) << 4) + (L >> 2);
  const int scol = ((w & 1) << 5) + (((L & 3) * 8) ^ ((L & 32) ? 16 : 0));
  unsigned aoff[4], boff[3];
#pragma unroll
  for (int j = 0; j < 4; ++j)
    aoff[j] = (unsigned)(m0 + j * 64 + lA) * (unsigned)K + scol;
#pragma unroll
  for (int j = 0; j < 3; ++j)
    boff[j] = (unsigned)(n0 + j * 64 + lA) * (unsigned)K + scol;
  const int ldst = w * 512;

  const int sq = (quad * 8) ^ ((lane16 & 8) << 1);
  const int rbase = lane16 * 32 + sq;

  floatx4 acc[8][3] = {};

  GLOAD_LDS16(A + aoff[0], &As[0][0 * 4096 + ldst]);
  GLOAD_LDS16(A + aoff[1], &As[0][1 * 4096 + ldst]);
  GLOAD_LDS16(A + aoff[2], &As[0][2 * 4096 + ldst]);
  GLOAD_LDS16(A + aoff[3], &As[0][3 * 4096 + ldst]);
  GLOAD_LDS16(Bt + boff[0], &Bs[0][0 * 4096 + ldst]);
  GLOAD_LDS16(Bt + boff[1], &Bs[0][1 * 4096 + ldst]);
  GLOAD_LDS16(Bt + boff[2], &Bs[0][2 * 4096 + ldst]);
  GLOAD_LDS16(Bt + boff[0] + 64, &Bs[1][0 * 4096 + ldst]);
  GLOAD_LDS16(Bt + boff[1] + 64, &Bs[1][1 * 4096 + ldst]);
  GLOAD_LDS16(Bt + boff[2] + 64, &Bs[1][2 * 4096 + ldst]);
  asm volatile("s_waitcnt vmcnt(3)" ::: "memory");
  __builtin_amdgcn_sched_barrier(0);
  __builtin_amdgcn_s_barrier();

  const int NT = K >> 6;  // 32
  short8 a[4][2], b[3][2];

  for (int t = 0; t < NT; ++t) {
    const int c = t & 1;
    const unsigned kn1 = (unsigned)(t + 1) << 6;
    const unsigned kn2 = (unsigned)(t + 2) << 6;
    const unsigned short* Ac = &As[c][0];
    const unsigned short* Bc = &Bs[c][0];

    // P0: read a-lo(8) + b(6); stage A(t+1); 24 MFMA
#pragma unroll
    for (int mi = 0; mi < 4; ++mi)
#pragma unroll
      for (int kk = 0; kk < 2; ++kk)
        a[mi][kk] = *(const short8*)(Ac + (wm * 2) * 4096 +
                                     ((mi * 2 + kk) * 512) + rbase);
#pragma unroll
    for (int ni = 0; ni < 3; ++ni) {
      const int f = wn * 3 + ni;
#pragma unroll
      for (int kk = 0; kk < 2; ++kk)
        b[ni][kk] = *(const short8*)(Bc + (f >> 2) * 4096 +
                                     (((f & 3) * 2 + kk) * 512) + rbase);
    }
    GLOAD_LDS16(A + aoff[0] + kn1, &As[c ^ 1][0 * 4096 + ldst]);
    GLOAD_LDS16(A + aoff[1] + kn1, &As[c ^ 1][1 * 4096 + ldst]);
    GLOAD_LDS16(A + aoff[2] + kn1, &As[c ^ 1][2 * 4096 + ldst]);
    GLOAD_LDS16(A + aoff[3] + kn1, &As[c ^ 1][3 * 4096 + ldst]);
    __builtin_amdgcn_s_setprio(1);
#pragma unroll
    for (int mi = 0; mi < 4; ++mi)
#pragma unroll
      for (int ni = 0; ni < 3; ++ni)
#pragma unroll
        for (int kk = 0; kk < 2; ++kk)
          acc[mi][ni] = __builtin_amdgcn_mfma_f32_16x16x32_bf16(
              a[mi][kk], b[ni][kk], acc[mi][ni], 0, 0, 0);
    __builtin_amdgcn_s_setprio(0);
    __builtin_amdgcn_sched_barrier(0);
    __builtin_amdgcn_s_barrier();

    // P1: read a-hi(8); stage B(t+2); 24 MFMA; vmcnt(3)
#pragma unroll
    for (int mi = 0; mi < 4; ++mi)
#pragma unroll
      for (int kk = 0; kk < 2; ++kk)
        a[mi][kk] = *(const short8*)(Ac + (wm * 2 + 1) * 4096 +
                                     ((mi * 2 + kk) * 512) + rbase);
    GLOAD_LDS16(Bt + boff[0] + kn2, &Bs[c][0 * 4096 + ldst]);
    GLOAD_LDS16(Bt + boff[1] + kn2, &Bs[c][1 * 4096 + ldst]);
    GLOAD_LDS16(Bt + boff[2] + kn2, &Bs[c][2 * 4096 + ldst]);
    __builtin_amdgcn_s_setprio(1);
#pragma unroll
    for (int mi = 0; mi < 4; ++mi)
#pragma unroll
      for (int ni = 0; ni < 3; ++ni)
#pragma unroll
        for (int kk = 0; kk < 2; ++kk)
          acc[4 + mi][ni] = __builtin_amdgcn_mfma_f32_16x16x32_bf16(
              a[mi][kk], b[ni][kk], acc[4 + mi][ni], 0, 0, 0);
    __builtin_amdgcn_s_setprio(0);
    asm volatile("s_waitcnt vmcnt(3)" ::: "memory");
    __builtin_amdgcn_sched_barrier(0);
    __builtin_amdgcn_s_barrier();
  }

  // epilogue
#pragma unroll
  for (int ni = 0; ni < 3; ++ni) {
    const int col = n0 + wn * 48 + ni * 16 + lane16;
    const float bv = bias[col];
#pragma unroll
    for (int mi = 0; mi < 8; ++mi) {
      const int row = m0 + wm * 128 + mi * 16 + quad * 4;
#pragma unroll
      for (int r = 0; r < 4; ++r)
        store_out(&C[(size_t)(row + r) * N + col], acc[mi][ni][r] + bv);
    }
  }
}

// ---------------------------------------------------------------------------
// 256x128 bf16 GEMM (BK=64): out-projection, grid 256 = 1 round (unchanged).
// ---------------------------------------------------------------------------
template <typename OutT>
__global__ __launch_bounds__(512, 2) void gemm_bf16_256x128(
    const unsigned short* __restrict__ A, const unsigned short* __restrict__ Bt,
    const float* __restrict__ bias, OutT* __restrict__ C,
    int M, int N, int K) {
  __shared__ __align__(16) unsigned short As[2][16384];  // 256x64
  __shared__ __align__(16) unsigned short Bs[2][8192];   // 128x64

  const int tid = threadIdx.x;
  const int w = tid >> 6;
  const int L = tid & 63;
  const int lane16 = L & 15;
  const int quad = L >> 4;
  const int wm = w >> 2;   // 0..1
  const int wn = w & 3;    // 0..3

  const int nby = M >> 8;          // 16
  const int q8 = gridDim.x >> 3;   // 32
  const int wg = (blockIdx.x & 7) * q8 + (blockIdx.x >> 3);
  const int by = wg % nby;
  const int bx = wg / nby;
  const int m0 = by << 8;
  const int n0 = bx << 7;

  const int lA = ((w >> 1) << 4) + (L >> 2);
  const int scol = ((w & 1) << 5) + (((L & 3) * 8) ^ ((L & 32) ? 16 : 0));
  unsigned aoff[4], boff[2];
#pragma unroll
  for (int j = 0; j < 4; ++j)
    aoff[j] = (unsigned)(m0 + j * 64 + lA) * (unsigned)K + scol;
#pragma unroll
  for (int j = 0; j < 2; ++j)
    boff[j] = (unsigned)(n0 + j * 64 + lA) * (unsigned)K + scol;
  const int ldst = w * 512;

  const int sq = (quad * 8) ^ ((lane16 & 8) << 1);
  const int rbase = lane16 * 32 + sq;

  floatx4 acc[8][2] = {};

  GLOAD_LDS16(A + aoff[0], &As[0][0 * 4096 + ldst]);
  GLOAD_LDS16(A + aoff[1], &As[0][1 * 4096 + ldst]);
  GLOAD_LDS16(A + aoff[2], &As[0][2 * 4096 + ldst]);
  GLOAD_LDS16(A + aoff[3], &As[0][3 * 4096 + ldst]);
  GLOAD_LDS16(Bt + boff[0], &Bs[0][0 * 4096 + ldst]);
  GLOAD_LDS16(Bt + boff[1], &Bs[0][1 * 4096 + ldst]);
  GLOAD_LDS16(Bt + boff[0] + 64, &Bs[1][0 * 4096 + ldst]);
  GLOAD_LDS16(Bt + boff[1] + 64, &Bs[1][1 * 4096 + ldst]);
  asm volatile("s_waitcnt vmcnt(2)" ::: "memory");
  __builtin_amdgcn_sched_barrier(0);
  __builtin_amdgcn_s_barrier();

  const int NT = K >> 6;  // 32
  short8 a[4][2], b[2][2];

  for (int t = 0; t < NT; ++t) {
    const int c = t & 1;
    const unsigned kn1 = (unsigned)(t + 1) << 6;
    const unsigned kn2 = (unsigned)(t + 2) << 6;
    const unsigned short* Ac = &As[c][0];
    const unsigned short* Bc = &Bs[c][0];

    // P0: read a-lo(8) + b(4); stage A(t+1); 16 MFMA
#pragma unroll
    for (int mi = 0; mi < 4; ++mi)
#pragma unroll
      for (int kk = 0; kk < 2; ++kk)
        a[mi][kk] = *(const short8*)(Ac + (wm * 2) * 4096 +
                                     ((mi * 2 + kk) * 512) + rbase);
#pragma unroll
    for (int ni = 0; ni < 2; ++ni) {
      const int f = wn * 2 + ni;
#pragma unroll
      for (int kk = 0; kk < 2; ++kk)
        b[ni][kk] = *(const short8*)(Bc + (f >> 2) * 4096 +
                                     (((f & 3) * 2 + kk) * 512) + rbase);
    }
    GLOAD_LDS16(A + aoff[0] + kn1, &As[c ^ 1][0 * 4096 + ldst]);
    GLOAD_LDS16(A + aoff[1] + kn1, &As[c ^ 1][1 * 4096 + ldst]);
    GLOAD_LDS16(A + aoff[2] + kn1, &As[c ^ 1][2 * 4096 + ldst]);
    GLOAD_LDS16(A + aoff[3] + kn1, &As[c ^ 1][3 * 4096 + ldst]);
    __builtin_amdgcn_s_setprio(1);
#pragma unroll
    for (int mi = 0; mi < 4; ++mi)
#pragma unroll
      for (int ni = 0; ni < 2; ++ni)
#pragma unroll
        for (int kk = 0; kk < 2; ++kk)
          acc[mi][ni] = __builtin_amdgcn_mfma_f32_16x16x32_bf16(
              a[mi][kk], b[ni][kk], acc[mi][ni], 0, 0, 0);
    __builtin_amdgcn_s_setprio(0);
    __builtin_amdgcn_sched_barrier(0);
    __builtin_amdgcn_s_barrier();

    // P1: read a-hi(8); stage B(t+2); 16 MFMA; vmcnt(2)
#pragma unroll
    for (int mi = 0; mi < 4; ++mi)
#pragma unroll
      for (int kk = 0; kk < 2; ++kk)
        a[mi][kk] = *(const short8*)(Ac + (wm * 2 + 1) * 4096 +
                                     ((mi * 2 + kk) * 512) + rbase);
    GLOAD_LDS16(Bt + boff[0] + kn2, &Bs[c][0 * 4096 + ldst]);
    GLOAD_LDS16(Bt + boff[1] + kn2, &Bs[c][1 * 4096 + ldst]);
    __builtin_amdgcn_s_setprio(1);
#pragma unroll
    for (int mi = 0; mi < 4; ++mi)
#pragma unroll
      for (int ni = 0; ni < 2; ++ni)
#pragma unroll
        for (int kk = 0; kk < 2; ++kk)
          acc[4 + mi][ni] = __builtin_amdgcn_mfma_f32_16x16x32_bf16(
              a[mi][kk], b[ni][kk], acc[4 + mi][ni], 0, 0, 0);
    __builtin_amdgcn_s_setprio(0);
    asm volatile("s_waitcnt vmcnt(2)" ::: "memory");
    __builtin_amdgcn_sched_barrier(0);
    __builtin_amdgcn_s_barrier();
  }

  // epilogue
#pragma unroll
  for (int ni = 0; ni < 2; ++ni) {
    const int col = n0 + wn * 32 + ni * 16 + lane16;
    const float bv = bias[col];
#pragma unroll
    for (int mi = 0; mi < 8; ++mi) {
      const int row = m0 + wm * 128 + mi * 16 + quad * 4;
#pragma unroll
      for (int r = 0; r < 4; ++r)
        store_out(&C[(size_t)(row + r) * N + col], acc[mi][ni][r] + bv);
    }
  }
}

// ---------------------------------------------------------------------------
// Merged VECTORIZED rotary (blocks 0..2047) + V transpose (2048..4095).
// Rotary: each thread owns 8 consecutive d-values of one (b,s,h) row:
// short8 loads at (d0, d0+64) for q and k -> 16B/lane coalesced (was 2B/lane
// scalar = Common-mistake #2). threads = B*S*H*8 = 524288 = 2048 blocks.
// ---------------------------------------------------------------------------
__global__ __launch_bounds__(256) void rope_transpose(
    unsigned short* __restrict__ qkv, unsigned short* __restrict__ vt) {
  if (blockIdx.x < 2048) {
    const int idx = blockIdx.x * 256 + threadIdx.x;  // 0..524287
    const int d0 = (idx & 7) * 8;
    const int h = (idx >> 3) & (HH - 1);
    const int s = (idx >> 7) & (SS - 1);
    const int b = idx >> 18;

    const size_t base = ((size_t)b * SS + s) * FF + h * DD;
    unsigned short* q = qkv + base;
    unsigned short* k = qkv + base + EE;

    short8 qlo = *(const short8*)(q + d0);
    short8 qhi = *(const short8*)(q + d0 + 64);
    short8 klo = *(const short8*)(k + d0);
    short8 khi = *(const short8*)(k + d0 + 64);
    short8 qlo_o, qhi_o, klo_o, khi_o;
    const float sf = (float)s;
#pragma unroll
    for (int j = 0; j < 8; ++j) {
      const float inv_freq = __expf(-(float)(d0 + j) * 0.14391156509f);
      float sn, c;
      __sincosf(sf * inv_freq, &sn, &c);
      const float q1 = bf2f((unsigned short)qlo[j]);
      const float q2 = bf2f((unsigned short)qhi[j]);
      qlo_o[j] = (short)f2bf(q1 * c - q2 * sn);
      qhi_o[j] = (short)f2bf(q2 * c + q1 * sn);
      const float k1 = bf2f((unsigned short)klo[j]);
      const float k2 = bf2f((unsigned short)khi[j]);
      klo_o[j] = (short)f2bf(k1 * c - k2 * sn);
      khi_o[j] = (short)f2bf(k2 * c + k1 * sn);
    }
    *(short8*)(q + d0) = qlo_o;
    *(short8*)(q + d0 + 64) = qhi_o;
    *(short8*)(k + d0) = klo_o;
    *(short8*)(k + d0 + 64) = khi_o;
  } else {
    // V transpose: [b][s][h][d] -> vt[b*H+h][d][s]
    __shared__ unsigned short T[64][72];
    const int idx = blockIdx.x - 2048;
    const int t = threadIdx.x;
    const int s0 = (idx & 31) * 64;
    const int d0 = ((idx >> 5) & 1) * 64;
    const int bh = idx >> 6;
    const int b = bh >> 4, h = bh & 15;
    {
      const int r = t >> 2, c = (t & 3) * 16;
      const unsigned short* src =
          qkv + ((size_t)b * SS + s0 + r) * FF + 2 * EE + h * DD + d0 + c;
      const uint4 u0 = *(const uint4*)src;
      const uint4 u1 = *(const uint4*)(src + 8);
      *(uint4*)&T[r][c] = u0;
      *(uint4*)&T[r][c + 8] = u1;
    }
    __syncthreads();
    {
      const int rr = t >> 2, cc = (t & 3) * 16;
      unsigned short vals[16];
#pragma unroll
      for (int j = 0; j < 16; ++j) vals[j] = T[cc + j][rr];
      unsigned short* dst =
          vt + (size_t)bh * DD * SS + (size_t)(d0 + rr) * SS + s0 + cc;
      *(uint4*)dst = *(uint4*)&vals[0];
      *(uint4*)(dst + 8) = *(uint4*)&vals[8];
    }
  }
}

// ---------------------------------------------------------------------------
// MFMA flash attention, causal: 4 waves x 32 q-rows, KVBLK=64 (unchanged
// from round 9). LDS 80 KiB -> 2 blocks/CU; Ssh/V XOR swizzles; LPT +
// XCD co-location + defer-max.
// ---------------------------------------------------------------------------
#define ATQ 128
#define ATK 64
#define NQT (SS / ATQ)  // 16

__global__ __launch_bounds__(256, 2) void attn_mfma(
    const unsigned short* __restrict__ qkv,
    const unsigned short* __restrict__ vt,
    unsigned short* __restrict__ ctx) {
  __shared__ __align__(16) unsigned short Ksh[2][ATK * DD];  // [kk][d] 16KB
  __shared__ __align__(16) unsigned short Vsh[2][DD * ATK];  // [d][kk] 16KB
  __shared__ __align__(16) unsigned short Ssh[ATQ][64];      // P, swizzled

  const int tid = threadIdx.x;
  const int L = tid & 63;
  const int w = tid >> 6;          // 0..3
  const int lane16 = L & 15;
  const int quad = L >> 4;

  const int flat = blockIdx.x;        // 0..511
  const int bh_lin = flat & 31;       // fastest -> flat%8 const per bh
  const int qb = (NQT - 1) - (flat >> 5);  // heavy q-tiles first (LPT)
  const int b = bh_lin >> 4;
  const int h = bh_lin & 15;
  const int bh = b * HH + h;
  const float scale = 0.08838834764831845f;

  // staging: 4 rounds K + 4 rounds V, 256 thr x 16B = 4KB per round
  size_t koff[4], voff[4];
#pragma unroll
  for (int j = 0; j < 4; ++j) {
    const int ik = j * 256 + tid;
    const int kk = ik >> 4;
    const int ock = (ik & 15) ^ (kk & 15);
    koff[j] = ((size_t)b * SS + kk) * FF + EE + h * DD + ock * 8;
    const int d = ik >> 3;
    const int ocv = (ik & 7) ^ (d & 7);
    voff[j] = (size_t)bh * DD * SS + (size_t)d * SS + ocv * 8;
  }
  const int dstb = w * 512;  // per-wave ushort offset within a 4KB round

  const int q0 = qb * ATQ;

  // Q frags (B-operand): wave w owns rows q0 + w*32 + mi*16 + lane16
  short8 qf[2][4];
#pragma unroll
  for (int mi = 0; mi < 2; ++mi) {
    const int q = q0 + w * 32 + mi * 16 + lane16;
    const unsigned short* qp =
        qkv + ((size_t)b * SS + q) * FF + h * DD + quad * 8;
#pragma unroll
    for (int dc = 0; dc < 4; ++dc)
      qf[mi][dc] = *(const short8*)(qp + dc * 32);
  }

  floatx4 acc[8][2] = {};
  float m_i[2] = {-3.0e38f, -3.0e38f};
  float l_i[2] = {0.0f, 0.0f};

  const int nkt = 2 * qb + 2;
  const int mykt = 2 * qb + (w >> 1);

  // prologue: stage tile 0 -> buf 0
#pragma unroll
  for (int j = 0; j < 4; ++j) {
    GLOAD_LDS16(qkv + koff[j], &Ksh[0][j * 2048 + dstb]);
    GLOAD_LDS16(vt + voff[j], &Vsh[0][j * 2048 + dstb]);
  }

  for (int kt = 0; kt < nkt; ++kt) {
    const int cur = kt & 1;
    __syncthreads();  // drains stage(kt)
    if (kt + 1 < nkt) {
      const size_t ka = (size_t)(kt + 1) * ATK * FF;
      const int va = (kt + 1) * ATK;
#pragma unroll
      for (int j = 0; j < 4; ++j) {
        GLOAD_LDS16(qkv + koff[j] + ka, &Ksh[cur ^ 1][j * 2048 + dstb]);
        GLOAD_LDS16(vt + voff[j] + va, &Vsh[cur ^ 1][j * 2048 + dstb]);
      }
    }
    if (kt > mykt) continue;  // fully-masked tile for this wave
    const int k0 = kt * ATK;
    const unsigned short* Kc = Ksh[cur];
    const unsigned short* Vc = Vsh[cur];

    // --- S^T = K x Q^T : 64 kk x 32 q per wave (32 MFMA) ---
    floatx4 st[4][2] = {};
    __builtin_amdgcn_s_setprio(1);
#pragma unroll
    for (int kkt = 0; kkt < 4; ++kkt) {
      const unsigned short* krow = Kc + (kkt * 16 + lane16) * 128;
#pragma unroll
      for (int dc = 0; dc < 4; ++dc) {
        const short8 kf =
            *(const short8*)(krow + ((dc * 4 + quad) ^ lane16) * 8);
#pragma unroll
        for (int mi = 0; mi < 2; ++mi)
          st[kkt][mi] = __builtin_amdgcn_mfma_f32_16x16x32_bf16(
              kf, qf[mi][dc], st[kkt][mi], 0, 0, 0);
      }
    }
    __builtin_amdgcn_s_setprio(0);

    // --- scale + causal mask (diagonal tile only) ---
    const bool needmask = (kt == mykt);
#pragma unroll
    for (int mi = 0; mi < 2; ++mi) {
      const int q_glob = q0 + w * 32 + mi * 16 + lane16;
#pragma unroll
      for (int kkt = 0; kkt < 4; ++kkt) {
        const int kkb = k0 + kkt * 16 + quad * 4;
#pragma unroll
        for (int r = 0; r < 4; ++r) {
          float v = st[kkt][mi][r] * scale;
          if (needmask && (kkb + r) > q_glob) v = -3.0e38f;
          st[kkt][mi][r] = v;
        }
      }
    }

    // --- online softmax (T13 defer-max), 16 vals per mi ---
#pragma unroll
    for (int mi = 0; mi < 2; ++mi) {
      float tm = -3.0e38f;
#pragma unroll
      for (int kkt = 0; kkt < 4; ++kkt)
#pragma unroll
        for (int r = 0; r < 4; ++r) tm = fmaxf(tm, st[kkt][mi][r]);
      tm = fmaxf(tm, __shfl_xor(tm, 16));
      tm = fmaxf(tm, __shfl_xor(tm, 32));

      const bool need = !__all(tm - m_i[mi] <= 8.0f);
      if (need) {
        const float mn = fmaxf(m_i[mi], tm);
        const float alpha = __expf(m_i[mi] - mn);
        m_i[mi] = mn;
        l_i[mi] *= alpha;
#pragma unroll
        for (int dt = 0; dt < 8; ++dt)
#pragma unroll
          for (int r = 0; r < 4; ++r) acc[dt][mi][r] *= alpha;
      }

      float rs = 0.0f;
#pragma unroll
      for (int kkt = 0; kkt < 4; ++kkt)
#pragma unroll
        for (int r = 0; r < 4; ++r) {
          const float p = __expf(st[kkt][mi][r] - m_i[mi]);
          st[kkt][mi][r] = p;
          rs += p;
        }
      rs += __shfl_xor(rs, 16);
      rs += __shfl_xor(rs, 32);
      l_i[mi] += rs;

      // P write: row q, slot (kkt*4+quad) ^ 2*(q&7)  (bit0 untouched)
      const int row = w * 32 + mi * 16 + lane16;
      const int sw = 2 * (lane16 & 7);
#pragma unroll
      for (int kkt = 0; kkt < 4; ++kkt) {
        ushort4 pk;
        pk.x = f2bf(st[kkt][mi][0]);
        pk.y = f2bf(st[kkt][mi][1]);
        pk.z = f2bf(st[kkt][mi][2]);
        pk.w = f2bf(st[kkt][mi][3]);
        *(ushort4*)(&Ssh[row][((kkt * 4 + quad) ^ sw) * 4]) = pk;
      }
    }

    // --- O^T += V^T x P^T : 128 d x 32 q, contraction 64 kk (32 MFMA) ---
    short8 pa[2][2];
#pragma unroll
    for (int mi = 0; mi < 2; ++mi) {
      const int row = w * 32 + mi * 16 + lane16;
      const int sw = 2 * (lane16 & 7);
#pragma unroll
      for (int ks = 0; ks < 2; ++ks)
        pa[mi][ks] =
            *(const short8*)(&Ssh[row][((ks * 8 + quad * 2) ^ sw) * 4]);
    }
    __builtin_amdgcn_s_setprio(1);
#pragma unroll
    for (int dt = 0; dt < 8; ++dt) {
      const unsigned short* vrow = Vc + (dt * 16 + lane16) * 64;
#pragma unroll
      for (int ks = 0; ks < 2; ++ks) {
        const short8 vf =
            *(const short8*)(vrow + (((ks * 4 + quad) ^ (lane16 & 7)) * 8));
#pragma unroll
        for (int mi = 0; mi < 2; ++mi)
          acc[dt][mi] = __builtin_amdgcn_mfma_f32_16x16x32_bf16(
              vf, pa[mi][ks], acc[dt][mi], 0, 0, 0);
      }
    }
    __builtin_amdgcn_s_setprio(0);
  }

  // epilogue: O^T row=d=dt*16+quad*4+r, col=q = q0 + w*32 + mi*16 + lane16
#pragma unroll
  for (int mi = 0; mi < 2; ++mi) {
    const float inv = 1.0f / l_i[mi];
    const int q = q0 + w * 32 + mi * 16 + lane16;
    unsigned short* op = ctx + ((size_t)b * SS + q) * EE + h * DD + quad * 4;
#pragma unroll
    for (int dt = 0; dt < 8; ++dt) {
      ushort4 o;
      o.x = f2bf(acc[dt][mi][0] * inv);
      o.y = f2bf(acc[dt][mi][1] * inv);
      o.z = f2bf(acc[dt][mi][2] * inv);
      o.w = f2bf(acc[dt][mi][3] * inv);
      *(ushort4*)(op + dt * 16) = o;
    }
  }
}

// ---------------------------------------------------------------------------
// Launch
// ---------------------------------------------------------------------------
extern "C" void kernel_launch(void* const* d_in, const int* in_sizes, int n_in,
                              void* d_out, int out_size, void* d_ws,
                              size_t ws_size, hipStream_t stream) {
  const float* x    = (const float*)d_in[0];
  const float* wqkv = (const float*)d_in[1];
  const float* bqkv = (const float*)d_in[2];
  const float* wout = (const float*)d_in[3];
  const float* bout = (const float*)d_in[4];
  float* out = (float*)d_out;

  unsigned short* qkvb = (unsigned short*)d_ws;      // 25165824 elems
  unsigned short* xb   = qkvb + (size_t)25165824;    //  8388608
  unsigned short* wqb  = xb + (size_t)8388608;       // 12582912
  unsigned short* ctxb = wqb + (size_t)12582912;     //  8388608
  unsigned short* wob  = ctxb + (size_t)8388608;     //  4194304
  unsigned short* vtb  = wob + (size_t)4194304;      //  8388608

  const int M = BB * SS;  // 4096

  // all three casts in one launch: (2097152 + 3145728 + 1048576)/256 = 24576
  cast_all<<<24576, 256, 0, stream>>>(x, wqkv, wout, xb, wqb, wob);

  {
    // 256x192 balanced grid: 16 x 32 = 512 blocks = exactly 2 rounds
    gemm_bf16_256x192<unsigned short><<<dim3(512), 512, 0, stream>>>(
        xb, wqb, bqkv, qkvb, M, FF, EE);
  }
  {
    // vectorized rotary (2048 blocks) + V transpose (2048 blocks)
    rope_transpose<<<4096, 256, 0, stream>>>(qkvb, vtb);
  }
  {
    // 4 waves x 32 rows, KVBLK=64: 512 blocks, 2 blocks/CU
    attn_mfma<<<dim3(512), 256, 0, stream>>>(qkvb, vtb, ctxb);
  }
  {
    // out-projection: 256x128 balanced grid, 16 x 16 = 256 blocks = 1 round
    gemm_bf16_256x128<float><<<dim3(256), 512, 0, stream>>>(
        ctxb, wob, bout, out, M, EE, EE);
  }
}